// Round 6
// baseline (1601.198 us; speedup 1.0000x reference)
//
#include <hip/hip_runtime.h>
#include <math.h>

#define H 128
#define BN_EPS 1e-5f

typedef __attribute__((ext_vector_type(8))) short bf16x8;
typedef __attribute__((ext_vector_type(4))) float f32x4;

__device__ __forceinline__ unsigned short f2bf(float f) {
    unsigned int u = __float_as_uint(f);
    u += 0x7fffu + ((u >> 16) & 1u);
    return (unsigned short)(u >> 16);
}
__device__ __forceinline__ float bf2f(unsigned short s) {
    return __uint_as_float(((unsigned int)s) << 16);
}
__device__ __forceinline__ f32x4 mfma16(bf16x8 a, bf16x8 b, f32x4 c) {
    return __builtin_amdgcn_mfma_f32_16x16x32_bf16(a, b, c, 0, 0, 0);
}

// ---------------------------------------------------------------------------
// Weight fragment pre-transpose into MFMA B-operand layout (bf16)
// ---------------------------------------------------------------------------
__device__ __forceinline__ void wfrag_one(const float* __restrict__ src,
                                          unsigned short* __restrict__ dst,
                                          int K, int N, int idx) {
    int l = idx & 63;
    int rest = idx >> 6;
    int ntn = N >> 4;
    int nt = rest % ntn;
    int kc = rest / ntn;
    int n = nt * 16 + (l & 15);
    int k0 = kc * 32 + (l >> 4) * 8;
    bf16x8 v;
    #pragma unroll
    for (int j = 0; j < 8; ++j) {
        int k = k0 + j;
        v[j] = (short)((k < K) ? f2bf(src[(size_t)k * N + n]) : 0);
    }
    *(bf16x8*)(dst + (size_t)idx * 8) = v;
}

__global__ __launch_bounds__(256)
void wfrag_all(const float* __restrict__ W1, const float* __restrict__ W2,
               const float* __restrict__ pu, const float* __restrict__ pr,
               const float* __restrict__ Wl, const float* __restrict__ Wr,
               unsigned short* __restrict__ W1f, unsigned short* __restrict__ W2f,
               unsigned short* __restrict__ puf, unsigned short* __restrict__ prf,
               unsigned short* __restrict__ sageWf) {
    int bx = blockIdx.x;
    if (bx < 26) {
        int idx = bx * 256 + threadIdx.x;
        if (idx < 4608)      wfrag_one(W1, W1f, 272, 128, idx);          // K=272 pad 288
        else if (idx < 5632) wfrag_one(W2, W2f, 128, 64, idx - 4608);
        else if (idx < 6144) wfrag_one(pu, puf, 32, 128, idx - 5632);
        else if (idx < 6656) wfrag_one(pr, prf, 32, 128, idx - 6144);
    } else {
        int idx = (bx - 26) * 256 + threadIdx.x;   // < 16384
        int seg = idx >> 11;
        int sub = idx & 2047;
        int lt = seg >> 1;                          // layer*2+type
        int half = seg & 1;                         // 0=Wl, 1=Wr
        const float* src = (half ? Wr : Wl) + (size_t)lt * H * H;
        unsigned short* dst = sageWf + (size_t)lt * 32768 + half * 16384;
        wfrag_one(src, dst, 128, 128, sub);
    }
}

// ---------------------------------------------------------------------------
// Input projection via MFMA: hb = bf16(x @ W + b)
// ---------------------------------------------------------------------------
__global__ __launch_bounds__(256)
void proj_kernel(const float* __restrict__ xu, const float* __restrict__ xr,
                 const unsigned short* __restrict__ puf, const float* __restrict__ bu,
                 const unsigned short* __restrict__ prf, const float* __restrict__ br,
                 unsigned short* __restrict__ hub, unsigned short* __restrict__ hrb,
                 int Nu, int Nr, int nbu) {
    int bx = blockIdx.x;
    const float* x; const unsigned short* Wf; const float* bias;
    unsigned short* hb; int N; int row0;
    if (bx < nbu) { x = xu; Wf = puf; bias = bu; hb = hub; N = Nu; row0 = bx * 64; }
    else          { x = xr; Wf = prf; bias = br; hb = hrb; N = Nr; row0 = (bx - nbu) * 64; }

    int tid = threadIdx.x, l = tid & 63, w = tid >> 6, l15 = l & 15, quad = l >> 4;
    int arow = row0 + w * 16 + l15;

    bf16x8 a = {0, 0, 0, 0, 0, 0, 0, 0};
    if (arow < N) {
        const float* xp = x + (size_t)arow * 32 + quad * 8;
        float4 v0 = *(const float4*)xp;
        float4 v1 = *(const float4*)(xp + 4);
        a[0] = (short)f2bf(v0.x); a[1] = (short)f2bf(v0.y);
        a[2] = (short)f2bf(v0.z); a[3] = (short)f2bf(v0.w);
        a[4] = (short)f2bf(v1.x); a[5] = (short)f2bf(v1.y);
        a[6] = (short)f2bf(v1.z); a[7] = (short)f2bf(v1.w);
    }
    f32x4 acc[8];
    #pragma unroll
    for (int nt = 0; nt < 8; ++nt) {
        bf16x8 b = *(const bf16x8*)(Wf + (size_t)(nt * 64 + l) * 8);
        acc[nt] = mfma16(a, b, (f32x4){0.f, 0.f, 0.f, 0.f});
    }
    #pragma unroll
    for (int reg = 0; reg < 4; ++reg) {
        int row = row0 + w * 16 + quad * 4 + reg;
        if (row < N) {
            #pragma unroll
            for (int nt = 0; nt < 8; ++nt) {
                int col = nt * 16 + l15;
                hb[(size_t)row * H + col] = f2bf(acc[nt][reg] + bias[col]);
            }
        }
    }
}

// ---------------------------------------------------------------------------
// CSR build (both edge types per dispatch)
// ---------------------------------------------------------------------------
__global__ __launch_bounds__(256)
void hist_kernel(const int* __restrict__ dstR, const int* __restrict__ dstU,
                 int* __restrict__ degR, int* __restrict__ degU, int E, int EB) {
    int bx = blockIdx.x;
    const int* dst = (bx < EB) ? dstR : dstU;
    int* deg = (bx < EB) ? degR : degU;
    int e = ((bx < EB) ? bx : bx - EB) * 256 + threadIdx.x;
    if (e < E) atomicAdd(&deg[dst[e]], 1);
}

__global__ __launch_bounds__(256)
void scan1_kernel(const int* __restrict__ degR, const int* __restrict__ degU,
                  int* __restrict__ partR, int* __restrict__ partU, int Nr, int Nu, int NBr) {
    int bx = blockIdx.x;
    const int* deg = (bx < NBr) ? degR : degU;
    int* part = (bx < NBr) ? partR : partU;
    int lb = (bx < NBr) ? bx : bx - NBr;
    int N = (bx < NBr) ? Nr : Nu;
    __shared__ int s[256];
    int t = threadIdx.x;
    int i = lb * 256 + t;
    s[t] = (i < N) ? deg[i] : 0;
    __syncthreads();
    for (int o = 128; o > 0; o >>= 1) {
        if (t < o) s[t] += s[t + o];
        __syncthreads();
    }
    if (t == 0) part[lb] = s[0];
}

__global__ __launch_bounds__(512)
void scan2_kernel(int* __restrict__ partR, int* __restrict__ partU, int nbR, int nbU) {
    int* part = (blockIdx.x == 0) ? partR : partU;
    int nb = (blockIdx.x == 0) ? nbR : nbU;
    __shared__ int s[512];
    int t = threadIdx.x;
    int v = (t < nb) ? part[t] : 0;
    s[t] = v;
    __syncthreads();
    for (int o = 1; o < 512; o <<= 1) {
        int x = (t >= o) ? s[t - o] : 0;
        __syncthreads();
        s[t] += x;
        __syncthreads();
    }
    if (t < nb) part[t] = s[t] - v;   // exclusive
}

__global__ __launch_bounds__(256)
void scan3_kernel(const int* __restrict__ degR, const int* __restrict__ degU,
                  const int* __restrict__ partR, const int* __restrict__ partU,
                  int* __restrict__ offR, int* __restrict__ offU, int Nr, int Nu, int NBr) {
    int bx = blockIdx.x;
    const int* deg = (bx < NBr) ? degR : degU;
    const int* part = (bx < NBr) ? partR : partU;
    int* off = (bx < NBr) ? offR : offU;
    int lb = (bx < NBr) ? bx : bx - NBr;
    int N = (bx < NBr) ? Nr : Nu;
    __shared__ int s[256];
    int t = threadIdx.x;
    int i = lb * 256 + t;
    int v = (i < N) ? deg[i] : 0;
    s[t] = v;
    __syncthreads();
    for (int o = 1; o < 256; o <<= 1) {
        int x = (t >= o) ? s[t - o] : 0;
        __syncthreads();
        s[t] += x;
        __syncthreads();
    }
    if (i < N) off[i] = part[lb] + s[t] - v;
    if (i == N - 1) off[N] = part[lb] + s[t];
}

// fill consumes deg via atomicSub; R side also records eperm (orig edge id)
// and epdst (dst node) per CSR slot for the CSR-ordered edge predictor.
__global__ __launch_bounds__(256)
void fill_kernel(const int* __restrict__ srcR, const int* __restrict__ dstR,
                 const int* __restrict__ srcU, const int* __restrict__ dstU,
                 const int* __restrict__ offR, const int* __restrict__ offU,
                 int* __restrict__ degR, int* __restrict__ degU,
                 int* __restrict__ eidR, int* __restrict__ eidU,
                 int* __restrict__ epermR, int* __restrict__ epdstR,
                 int E, int EB) {
    int bx = blockIdx.x;
    bool isR = bx < EB;
    const int* src = isR ? srcR : srcU;
    const int* dst = isR ? dstR : dstU;
    const int* off = isR ? offR : offU;
    int* deg = isR ? degR : degU;
    int* eid = isR ? eidR : eidU;
    int e = (isR ? bx : bx - EB) * 256 + threadIdx.x;
    if (e < E) {
        int d = dst[e];
        int p = off[d] + atomicSub(&deg[d], 1) - 1;
        eid[p] = src[e];
        if (isR) {
            epermR[p] = e;
            epdstR[p] = d;
        }
    }
}

// ---------------------------------------------------------------------------
// Degree sort (counting sort, 64 buckets): nodeperm groups equal-degree nodes
// so layer_kernel waves have uniform CSR-walk lengths.
// ---------------------------------------------------------------------------
__global__ __launch_bounds__(256)
void dhist_kernel(const int* __restrict__ off_r, const int* __restrict__ off_u,
                  int* __restrict__ bhist, int Nr, int Nu, int NBr) {
    int bx = blockIdx.x;
    bool isR = bx < NBr;
    const int* off = isR ? off_r : off_u;
    int* bh = bhist + (isR ? 0 : 64);
    int N = isR ? Nr : Nu;
    int n = (isR ? bx : bx - NBr) * 256 + threadIdx.x;
    if (n < N) {
        int d = off[n + 1] - off[n];
        atomicAdd(&bh[min(d, 63)], 1);
    }
}

__global__ __launch_bounds__(64)
void dscan_kernel(const int* __restrict__ bhist, int* __restrict__ boff) {
    __shared__ int s[64];
    int t = threadIdx.x;
    int base = blockIdx.x * 64;
    int v = bhist[base + t];
    s[t] = v;
    __syncthreads();
    for (int o = 1; o < 64; o <<= 1) {
        int x = (t >= o) ? s[t - o] : 0;
        __syncthreads();
        s[t] += x;
        __syncthreads();
    }
    boff[base + t] = s[t] - v;   // exclusive
}

__global__ __launch_bounds__(256)
void dscatter_kernel(const int* __restrict__ off_r, const int* __restrict__ off_u,
                     const int* __restrict__ boff, int* __restrict__ bcnt,
                     int* __restrict__ npr, int* __restrict__ npu,
                     int Nr, int Nu, int NBr) {
    int bx = blockIdx.x;
    bool isR = bx < NBr;
    const int* off = isR ? off_r : off_u;
    const int* bo = boff + (isR ? 0 : 64);
    int* bc = bcnt + (isR ? 0 : 64);
    int* np = isR ? npr : npu;
    int N = isR ? Nr : Nu;
    int n = (isR ? bx : bx - NBr) * 256 + threadIdx.x;
    if (n < N) {
        int b = min(off[n + 1] - off[n], 63);
        int pos = bo[b] + atomicAdd(&bc[b], 1);
        np[pos] = n;
    }
}

// ---------------------------------------------------------------------------
// Fused layer: gather-mean + SAGE + BN + ReLU + residual, both node types.
// Nodes processed in degree-sorted order via nodeperm (uniform wave walks).
// ---------------------------------------------------------------------------
__global__ __launch_bounds__(256)
void layer_kernel(const unsigned short* __restrict__ hu_o, const unsigned short* __restrict__ hr_o,
                  unsigned short* __restrict__ hu_n, unsigned short* __restrict__ hr_n,
                  const int* __restrict__ off_r, const int* __restrict__ eid_r,
                  const int* __restrict__ off_u, const int* __restrict__ eid_u,
                  const int* __restrict__ np_r, const int* __restrict__ np_u,
                  int Nu, int Nr, int nbr,
                  const unsigned short* __restrict__ WfR, const float* __restrict__ blR,
                  const float* __restrict__ gR, const float* __restrict__ bR,
                  const float* __restrict__ mR, const float* __restrict__ vR,
                  const unsigned short* __restrict__ WfU, const float* __restrict__ blU,
                  const float* __restrict__ gU, const float* __restrict__ bU,
                  const float* __restrict__ mU, const float* __restrict__ vU) {
    int bx = blockIdx.x;
    const unsigned short* gsrc; const unsigned short* own; unsigned short* outp;
    const int* off; const int* eid; const int* np; const unsigned short* Wf;
    const float *bl, *bg, *bb, *bm, *bv;
    int N, row0;
    if (bx < nbr) {
        gsrc = hu_o; own = hr_o; outp = hr_n; off = off_r; eid = eid_r; np = np_r;
        Wf = WfR; bl = blR; bg = gR; bb = bR; bm = mR; bv = vR;
        N = Nr; row0 = bx * 64;
    } else {
        gsrc = hr_o; own = hu_o; outp = hu_n; off = off_u; eid = eid_u; np = np_u;
        Wf = WfU; bl = blU; bg = gU; bb = bU; bm = mU; bv = vU;
        N = Nu; row0 = (bx - nbr) * 64;
    }

    __shared__ float sc[128], sh[128], bias[128];
    __shared__ int pidx[64];
    int tid = threadIdx.x;
    if (tid < 128) {
        float s = bg[tid] * rsqrtf(bv[tid] + BN_EPS);
        sc[tid] = s;
        sh[tid] = bb[tid] - bm[tid] * s;
        bias[tid] = bl[tid];
    }
    if (tid < 64) {
        int rr = row0 + tid;
        pidx[tid] = (rr < N) ? np[rr] : -1;
    }
    __syncthreads();

    int l = tid & 63, w = tid >> 6, l15 = l & 15, quad = l >> 4;
    int rb = w * 16 + l15;
    int phys = pidx[rb];
    bool rok = (phys >= 0);
    size_t rbase = (size_t)(rok ? phys : 0) * H;
    int s0 = rok ? off[phys] : 0;
    int s1 = rok ? off[phys + 1] : 0;

    // gather-mean into per-lane A-fragment slices (4 chunks x 8 elems)
    float ag[4][8];
    #pragma unroll
    for (int kc = 0; kc < 4; ++kc)
        #pragma unroll
        for (int j = 0; j < 8; ++j) ag[kc][j] = 0.0f;

    for (int i = s0; i < s1; ++i) {
        int s = eid[i];
        const unsigned short* rp = gsrc + (size_t)s * H + quad * 8;
        #pragma unroll
        for (int kc = 0; kc < 4; ++kc) {
            bf16x8 v = *(const bf16x8*)(rp + kc * 32);
            #pragma unroll
            for (int j = 0; j < 8; ++j) ag[kc][j] += bf2f((unsigned short)v[j]);
        }
    }
    float inv = (s1 > s0) ? 1.0f / (float)(s1 - s0) : 0.0f;

    f32x4 acc[8];
    #pragma unroll
    for (int nt = 0; nt < 8; ++nt) acc[nt] = (f32x4){0.f, 0.f, 0.f, 0.f};

    // chunks 0..3: aggregated neighbor mean
    #pragma unroll
    for (int kc = 0; kc < 4; ++kc) {
        bf16x8 a;
        #pragma unroll
        for (int j = 0; j < 8; ++j) a[j] = (short)f2bf(ag[kc][j] * inv);
        #pragma unroll
        for (int nt = 0; nt < 8; ++nt) {
            bf16x8 b = *(const bf16x8*)(Wf + (size_t)((kc * 8 + nt) * 64 + l) * 8);
            acc[nt] = mfma16(a, b, acc[nt]);
        }
    }
    // chunks 4..7: own row (root weight)
    #pragma unroll
    for (int kc = 4; kc < 8; ++kc) {
        bf16x8 a = rok ? *(const bf16x8*)(own + rbase + (kc - 4) * 32 + quad * 8)
                       : (bf16x8){0, 0, 0, 0, 0, 0, 0, 0};
        #pragma unroll
        for (int nt = 0; nt < 8; ++nt) {
            bf16x8 b = *(const bf16x8*)(Wf + (size_t)((kc * 8 + nt) * 64 + l) * 8);
            acc[nt] = mfma16(a, b, acc[nt]);
        }
    }

    // epilogue: bias -> BN -> ReLU -> + residual (bf16), scattered row writes
    #pragma unroll
    for (int reg = 0; reg < 4; ++reg) {
        int crb = w * 16 + quad * 4 + reg;
        int cphys = pidx[crb];
        if (cphys >= 0) {
            #pragma unroll
            for (int nt = 0; nt < 8; ++nt) {
                int col = nt * 16 + l15;
                float g = acc[nt][reg] + bias[col];
                g = g * sc[col] + sh[col];
                float hv = bf2f(own[(size_t)cphys * H + col]);
                outp[(size_t)cphys * H + col] = f2bf(fmaxf(g, 0.0f) + hv);
            }
        }
    }
}

// ---------------------------------------------------------------------------
// Edge predictor via MFMA, processed in CSR (dst-sorted) slot order:
// dst rows repeat ~deg times consecutively -> L1/L2 hits; src stays random.
// Per-edge arithmetic identical to edge-ordered version.
// ---------------------------------------------------------------------------
__global__ __launch_bounds__(256)
void ep_kernel(const unsigned short* __restrict__ hub, const unsigned short* __restrict__ hrb,
               const float* __restrict__ ea,
               const int* __restrict__ slot_src, const int* __restrict__ slot_dst,
               const int* __restrict__ slot_eid,
               const unsigned short* __restrict__ W1f, const float* __restrict__ b1,
               const float* __restrict__ bng, const float* __restrict__ bnb,
               const float* __restrict__ bnm, const float* __restrict__ bnv,
               const unsigned short* __restrict__ W2f, const float* __restrict__ b2,
               const float* __restrict__ W3, const float* __restrict__ b3,
               float* __restrict__ out, int E) {
    __shared__ unsigned short h1s[64][136];
    __shared__ int se[64], de[64], pe[64];
    __shared__ float sc1[128], sh1[128], bi1[128];

    int tid = threadIdx.x;
    int p0 = blockIdx.x * 64;
    if (tid < 64) {
        int p = p0 + tid;
        bool v = (p < E);
        se[tid] = v ? slot_src[p] : 0;
        de[tid] = v ? slot_dst[p] : 0;
        pe[tid] = v ? slot_eid[p] : 0;
    }
    if (tid < 128) {
        float s = bng[tid] * rsqrtf(bnv[tid] + BN_EPS);
        sc1[tid] = s;
        sh1[tid] = bnb[tid] - bnm[tid] * s;
        bi1[tid] = b1[tid];
    }
    __syncthreads();

    int l = tid & 63, w = tid >> 6, l15 = l & 15, quad = l >> 4;
    int arow = w * 16 + l15;
    size_t soff = (size_t)se[arow] * H;
    size_t doff = (size_t)de[arow] * H;
    int eorig = pe[arow];
    bool ev = (p0 + arow < E);

    f32x4 acc[8];
    #pragma unroll
    for (int nt = 0; nt < 8; ++nt) acc[nt] = (f32x4){0.f, 0.f, 0.f, 0.f};

    #pragma unroll
    for (int kc = 0; kc < 9; ++kc) {
        bf16x8 a;
        if (kc < 4) {
            a = *(const bf16x8*)(hub + soff + kc * 32 + quad * 8);
        } else if (kc < 8) {
            a = *(const bf16x8*)(hrb + doff + (kc - 4) * 32 + quad * 8);
        } else {
            a = (bf16x8){0, 0, 0, 0, 0, 0, 0, 0};
            if (quad < 2 && ev) {
                const float* p = ea + (size_t)eorig * 16 + quad * 8;
                float4 v0 = *(const float4*)p;
                float4 v1 = *(const float4*)(p + 4);
                a[0] = (short)f2bf(v0.x); a[1] = (short)f2bf(v0.y);
                a[2] = (short)f2bf(v0.z); a[3] = (short)f2bf(v0.w);
                a[4] = (short)f2bf(v1.x); a[5] = (short)f2bf(v1.y);
                a[6] = (short)f2bf(v1.z); a[7] = (short)f2bf(v1.w);
            }
        }
        #pragma unroll
        for (int nt = 0; nt < 8; ++nt) {
            bf16x8 b = *(const bf16x8*)(W1f + (size_t)((kc * 8 + nt) * 64 + l) * 8);
            acc[nt] = mfma16(a, b, acc[nt]);
        }
    }

    // phase-1 epilogue: bias -> relu -> bn -> bf16 h1s
    #pragma unroll
    for (int nt = 0; nt < 8; ++nt) {
        #pragma unroll
        for (int reg = 0; reg < 4; ++reg) {
            int row = w * 16 + quad * 4 + reg;
            int col = nt * 16 + l15;
            float z = acc[nt][reg] + bi1[col];
            z = fmaxf(z, 0.0f);
            z = z * sc1[col] + sh1[col];
            h1s[row][col] = f2bf(z);
        }
    }
    __syncthreads();

    // phase 2: h2 = relu(h1 @ W2 + b2), K=128, N=64
    f32x4 acc2[4];
    #pragma unroll
    for (int nt = 0; nt < 4; ++nt) acc2[nt] = (f32x4){0.f, 0.f, 0.f, 0.f};
    #pragma unroll
    for (int kc = 0; kc < 4; ++kc) {
        bf16x8 a2 = *(const bf16x8*)&h1s[w * 16 + l15][kc * 32 + quad * 8];
        #pragma unroll
        for (int nt = 0; nt < 4; ++nt) {
            bf16x8 b = *(const bf16x8*)(W2f + (size_t)((kc * 4 + nt) * 64 + l) * 8);
            acc2[nt] = mfma16(a2, b, acc2[nt]);
        }
    }

    // phase 3: per-row dot with W3 via quad shuffle reduction
    float part[4] = {0.f, 0.f, 0.f, 0.f};
    #pragma unroll
    for (int nt = 0; nt < 4; ++nt) {
        int col = nt * 16 + l15;
        float w3v = W3[col];
        float b2v = b2[col];
        #pragma unroll
        for (int reg = 0; reg < 4; ++reg)
            part[reg] += fmaxf(acc2[nt][reg] + b2v, 0.0f) * w3v;
    }
    #pragma unroll
    for (int m = 1; m < 16; m <<= 1) {
        #pragma unroll
        for (int reg = 0; reg < 4; ++reg)
            part[reg] += __shfl_xor(part[reg], m);
    }
    if (l15 < 4) {
        int row = w * 16 + quad * 4 + l15;
        if (p0 + row < E) {
            int eo = pe[row];
            out[eo] = 1.0f / (1.0f + expf(-(part[l15] + b3[0])));
        }
    }
}

// ---------------------------------------------------------------------------
extern "C" void kernel_launch(void* const* d_in, const int* in_sizes, int n_in,
                              void* d_out, int out_size, void* d_ws, size_t ws_size,
                              hipStream_t stream) {
    const float* x_u     = (const float*)d_in[0];
    const float* x_r     = (const float*)d_in[1];
    const float* eattr   = (const float*)d_in[2];
    const int*   ei_ut   = (const int*)d_in[3];
    const int*   ei_ru   = (const int*)d_in[4];
    const float* proj_uW = (const float*)d_in[5];
    const float* proj_ub = (const float*)d_in[6];
    const float* proj_rW = (const float*)d_in[7];
    const float* proj_rb = (const float*)d_in[8];
    const float* sage_Wl = (const float*)d_in[9];
    const float* sage_bl = (const float*)d_in[10];
    const float* sage_Wr = (const float*)d_in[11];
    const float* bn_g    = (const float*)d_in[12];
    const float* bn_b    = (const float*)d_in[13];
    const float* bn_m    = (const float*)d_in[14];
    const float* bn_v    = (const float*)d_in[15];
    const float* ep_W1   = (const float*)d_in[16];
    const float* ep_b1   = (const float*)d_in[17];
    const float* ep_bng  = (const float*)d_in[18];
    const float* ep_bnb  = (const float*)d_in[19];
    const float* ep_bnm  = (const float*)d_in[20];
    const float* ep_bnv  = (const float*)d_in[21];
    const float* ep_W2   = (const float*)d_in[22];
    const float* ep_b2   = (const float*)d_in[23];
    const float* ep_W3   = (const float*)d_in[24];
    const float* ep_b3   = (const float*)d_in[25];

    int Nu = in_sizes[0] / 32;
    int Nr = in_sizes[1] / 32;
    int E  = in_sizes[3] / 2;

    // ---- workspace ----
    unsigned short* us = (unsigned short*)d_ws;
    unsigned short* h0_u = us;   us += (size_t)Nu * H;
    unsigned short* h0_r = us;   us += (size_t)Nr * H;
    unsigned short* h1_u = us;   us += (size_t)Nu * H;
    unsigned short* h1_r = us;   us += (size_t)Nr * H;
    unsigned short* W1f  = us;   us += 36864;
    unsigned short* W2f  = us;   us += 8192;
    unsigned short* puf  = us;   us += 4096;
    unsigned short* prf  = us;   us += 4096;
    unsigned short* sageWf = us; us += 131072;
    int* ip     = (int*)us;
    int* off_r  = ip;  ip += Nr + 1;
    int* off_u  = ip;  ip += Nu + 1;
    int* deg_r  = ip;  ip += Nr;      // deg_r..bcnt contiguous (one memset)
    int* deg_u  = ip;  ip += Nu;
    int* bhist  = ip;  ip += 128;
    int* bcnt   = ip;  ip += 128;
    int* boff   = ip;  ip += 128;
    int* eid_r  = ip;  ip += E;
    int* eid_u  = ip;  ip += E;
    int* eperm_r = ip; ip += E;
    int* epdst_r = ip; ip += E;
    int* np_r   = ip;  ip += Nr;
    int* np_u   = ip;  ip += Nu;
    int* part_r = ip;  ip += 512;
    int* part_u = ip;  ip += 512;

    const int* ut_src = ei_ut;
    const int* ut_dst = ei_ut + E;
    const int* ru_src = ei_ru;
    const int* ru_dst = ei_ru + E;

    int EB  = (E + 255) / 256;
    int NBr = (Nr + 255) / 256;
    int NBu = (Nu + 255) / 256;

    // ---- weight fragments ----
    wfrag_all<<<90, 256, 0, stream>>>(ep_W1, ep_W2, proj_uW, proj_rW,
                                      sage_Wl, sage_Wr,
                                      W1f, W2f, puf, prf, sageWf);

    // ---- CSR build + degree sort ----
    hipMemsetAsync(deg_r, 0, (size_t)(Nr + Nu + 256) * sizeof(int), stream);
    hist_kernel<<<2 * EB, 256, 0, stream>>>(ut_dst, ru_dst, deg_r, deg_u, E, EB);
    scan1_kernel<<<NBr + NBu, 256, 0, stream>>>(deg_r, deg_u, part_r, part_u, Nr, Nu, NBr);
    scan2_kernel<<<2, 512, 0, stream>>>(part_r, part_u, NBr, NBu);
    scan3_kernel<<<NBr + NBu, 256, 0, stream>>>(deg_r, deg_u, part_r, part_u,
                                                off_r, off_u, Nr, Nu, NBr);
    fill_kernel<<<2 * EB, 256, 0, stream>>>(ut_src, ut_dst, ru_src, ru_dst,
                                            off_r, off_u, deg_r, deg_u,
                                            eid_r, eid_u, eperm_r, epdst_r, E, EB);
    dhist_kernel<<<NBr + NBu, 256, 0, stream>>>(off_r, off_u, bhist, Nr, Nu, NBr);
    dscan_kernel<<<2, 64, 0, stream>>>(bhist, boff);
    dscatter_kernel<<<NBr + NBu, 256, 0, stream>>>(off_r, off_u, boff, bcnt,
                                                   np_r, np_u, Nr, Nu, NBr);

    // ---- input projections ----
    int nbu = (Nu + 63) / 64, nbr = (Nr + 63) / 64;
    proj_kernel<<<nbu + nbr, 256, 0, stream>>>(x_u, x_r, puf, proj_ub, prf, proj_rb,
                                               h0_u, h0_r, Nu, Nr, nbu);

    // ---- 2 fused layers (ping-pong h0 -> h1 -> h0) ----
    for (int layer = 0; layer < 2; ++layer) {
        const unsigned short* iu = (layer == 0) ? h0_u : h1_u;
        const unsigned short* ir = (layer == 0) ? h0_r : h1_r;
        unsigned short* ou = (layer == 0) ? h1_u : h0_u;
        unsigned short* orr = (layer == 0) ? h1_r : h0_r;

        const unsigned short* Wf0 = sageWf + ((size_t)layer * 2 + 0) * 32768;
        const unsigned short* Wf1 = sageWf + ((size_t)layer * 2 + 1) * 32768;
        const float* bl0 = sage_bl + ((size_t)layer * 2 + 0) * H;
        const float* bl1 = sage_bl + ((size_t)layer * 2 + 1) * H;
        const float* g0 = bn_g + ((size_t)layer * 2 + 0) * H;   // user BN
        const float* b0 = bn_b + ((size_t)layer * 2 + 0) * H;
        const float* m0 = bn_m + ((size_t)layer * 2 + 0) * H;
        const float* v0 = bn_v + ((size_t)layer * 2 + 0) * H;
        const float* g1 = bn_g + ((size_t)layer * 2 + 1) * H;   // recipient BN
        const float* b1 = bn_b + ((size_t)layer * 2 + 1) * H;
        const float* m1 = bn_m + ((size_t)layer * 2 + 1) * H;
        const float* v1 = bn_v + ((size_t)layer * 2 + 1) * H;

        layer_kernel<<<nbr + nbu, 256, 0, stream>>>(
            iu, ir, ou, orr,
            off_r, eid_r, off_u, eid_u, np_r, np_u,
            Nu, Nr, nbr,
            Wf0, bl0, g1, b1, m1, v1,    // recipient side (edge type 0, BN type 1)
            Wf1, bl1, g0, b0, m0, v0);   // user side (edge type 1, BN type 0)
    }

    ep_kernel<<<(E + 63) / 64, 256, 0, stream>>>(h0_u, h0_r, eattr,
                                                 eid_r, epdst_r, eperm_r,
                                                 W1f, ep_b1,
                                                 ep_bng, ep_bnb, ep_bnm, ep_bnv,
                                                 W2f, ep_b2, ep_W3, ep_b3,
                                                 (float*)d_out, E);
}

// Round 7
// 595.951 us; speedup vs baseline: 2.6868x; 2.6868x over previous
//
#include <hip/hip_runtime.h>
#include <math.h>

#define H 128
#define BN_EPS 1e-5f

typedef __attribute__((ext_vector_type(8))) short bf16x8;
typedef __attribute__((ext_vector_type(4))) float f32x4;

__device__ __forceinline__ unsigned short f2bf(float f) {
    unsigned int u = __float_as_uint(f);
    u += 0x7fffu + ((u >> 16) & 1u);
    return (unsigned short)(u >> 16);
}
__device__ __forceinline__ float bf2f(unsigned short s) {
    return __uint_as_float(((unsigned int)s) << 16);
}
__device__ __forceinline__ f32x4 mfma16(bf16x8 a, bf16x8 b, f32x4 c) {
    return __builtin_amdgcn_mfma_f32_16x16x32_bf16(a, b, c, 0, 0, 0);
}

// ---------------------------------------------------------------------------
// Weight fragment pre-transpose into MFMA B-operand layout (bf16)
// ---------------------------------------------------------------------------
__device__ __forceinline__ void wfrag_one(const float* __restrict__ src,
                                          unsigned short* __restrict__ dst,
                                          int K, int N, int idx) {
    int l = idx & 63;
    int rest = idx >> 6;
    int ntn = N >> 4;
    int nt = rest % ntn;
    int kc = rest / ntn;
    int n = nt * 16 + (l & 15);
    int k0 = kc * 32 + (l >> 4) * 8;
    bf16x8 v;
    #pragma unroll
    for (int j = 0; j < 8; ++j) {
        int k = k0 + j;
        v[j] = (short)((k < K) ? f2bf(src[(size_t)k * N + n]) : 0);
    }
    *(bf16x8*)(dst + (size_t)idx * 8) = v;
}

__global__ __launch_bounds__(256)
void wfrag_all(const float* __restrict__ W1, const float* __restrict__ W2,
               const float* __restrict__ pu, const float* __restrict__ pr,
               const float* __restrict__ Wl, const float* __restrict__ Wr,
               unsigned short* __restrict__ W1f, unsigned short* __restrict__ W2f,
               unsigned short* __restrict__ puf, unsigned short* __restrict__ prf,
               unsigned short* __restrict__ sageWf) {
    int bx = blockIdx.x;
    if (bx < 26) {
        int idx = bx * 256 + threadIdx.x;
        if (idx < 4608)      wfrag_one(W1, W1f, 272, 128, idx);          // K=272 pad 288
        else if (idx < 5632) wfrag_one(W2, W2f, 128, 64, idx - 4608);
        else if (idx < 6144) wfrag_one(pu, puf, 32, 128, idx - 5632);
        else if (idx < 6656) wfrag_one(pr, prf, 32, 128, idx - 6144);
    } else {
        int idx = (bx - 26) * 256 + threadIdx.x;   // < 16384
        int seg = idx >> 11;
        int sub = idx & 2047;
        int lt = seg >> 1;                          // layer*2+type
        int half = seg & 1;                         // 0=Wl, 1=Wr
        const float* src = (half ? Wr : Wl) + (size_t)lt * H * H;
        unsigned short* dst = sageWf + (size_t)lt * 32768 + half * 16384;
        wfrag_one(src, dst, 128, 128, sub);
    }
}

// ---------------------------------------------------------------------------
// Input projection via MFMA: hb = bf16(x @ W + b)
// ---------------------------------------------------------------------------
__global__ __launch_bounds__(256)
void proj_kernel(const float* __restrict__ xu, const float* __restrict__ xr,
                 const unsigned short* __restrict__ puf, const float* __restrict__ bu,
                 const unsigned short* __restrict__ prf, const float* __restrict__ br,
                 unsigned short* __restrict__ hub, unsigned short* __restrict__ hrb,
                 int Nu, int Nr, int nbu) {
    int bx = blockIdx.x;
    const float* x; const unsigned short* Wf; const float* bias;
    unsigned short* hb; int N; int row0;
    if (bx < nbu) { x = xu; Wf = puf; bias = bu; hb = hub; N = Nu; row0 = bx * 64; }
    else          { x = xr; Wf = prf; bias = br; hb = hrb; N = Nr; row0 = (bx - nbu) * 64; }

    int tid = threadIdx.x, l = tid & 63, w = tid >> 6, l15 = l & 15, quad = l >> 4;
    int arow = row0 + w * 16 + l15;

    bf16x8 a = {0, 0, 0, 0, 0, 0, 0, 0};
    if (arow < N) {
        const float* xp = x + (size_t)arow * 32 + quad * 8;
        float4 v0 = *(const float4*)xp;
        float4 v1 = *(const float4*)(xp + 4);
        a[0] = (short)f2bf(v0.x); a[1] = (short)f2bf(v0.y);
        a[2] = (short)f2bf(v0.z); a[3] = (short)f2bf(v0.w);
        a[4] = (short)f2bf(v1.x); a[5] = (short)f2bf(v1.y);
        a[6] = (short)f2bf(v1.z); a[7] = (short)f2bf(v1.w);
    }
    f32x4 acc[8];
    #pragma unroll
    for (int nt = 0; nt < 8; ++nt) {
        bf16x8 b = *(const bf16x8*)(Wf + (size_t)(nt * 64 + l) * 8);
        acc[nt] = mfma16(a, b, (f32x4){0.f, 0.f, 0.f, 0.f});
    }
    #pragma unroll
    for (int reg = 0; reg < 4; ++reg) {
        int row = row0 + w * 16 + quad * 4 + reg;
        if (row < N) {
            #pragma unroll
            for (int nt = 0; nt < 8; ++nt) {
                int col = nt * 16 + l15;
                hb[(size_t)row * H + col] = f2bf(acc[nt][reg] + bias[col]);
            }
        }
    }
}

// ---------------------------------------------------------------------------
// CSR build (both edge types per dispatch)
// ---------------------------------------------------------------------------
__global__ __launch_bounds__(256)
void hist_kernel(const int* __restrict__ dstR, const int* __restrict__ dstU,
                 int* __restrict__ degR, int* __restrict__ degU, int E, int EB) {
    int bx = blockIdx.x;
    const int* dst = (bx < EB) ? dstR : dstU;
    int* deg = (bx < EB) ? degR : degU;
    int e = ((bx < EB) ? bx : bx - EB) * 256 + threadIdx.x;
    if (e < E) atomicAdd(&deg[dst[e]], 1);
}

__global__ __launch_bounds__(256)
void scan1_kernel(const int* __restrict__ degR, const int* __restrict__ degU,
                  int* __restrict__ partR, int* __restrict__ partU, int Nr, int Nu, int NBr) {
    int bx = blockIdx.x;
    const int* deg = (bx < NBr) ? degR : degU;
    int* part = (bx < NBr) ? partR : partU;
    int lb = (bx < NBr) ? bx : bx - NBr;
    int N = (bx < NBr) ? Nr : Nu;
    __shared__ int s[256];
    int t = threadIdx.x;
    int i = lb * 256 + t;
    s[t] = (i < N) ? deg[i] : 0;
    __syncthreads();
    for (int o = 128; o > 0; o >>= 1) {
        if (t < o) s[t] += s[t + o];
        __syncthreads();
    }
    if (t == 0) part[lb] = s[0];
}

__global__ __launch_bounds__(512)
void scan2_kernel(int* __restrict__ partR, int* __restrict__ partU, int nbR, int nbU) {
    int* part = (blockIdx.x == 0) ? partR : partU;
    int nb = (blockIdx.x == 0) ? nbR : nbU;
    __shared__ int s[512];
    int t = threadIdx.x;
    int v = (t < nb) ? part[t] : 0;
    s[t] = v;
    __syncthreads();
    for (int o = 1; o < 512; o <<= 1) {
        int x = (t >= o) ? s[t - o] : 0;
        __syncthreads();
        s[t] += x;
        __syncthreads();
    }
    if (t < nb) part[t] = s[t] - v;   // exclusive
}

__global__ __launch_bounds__(256)
void scan3_kernel(const int* __restrict__ degR, const int* __restrict__ degU,
                  const int* __restrict__ partR, const int* __restrict__ partU,
                  int* __restrict__ offR, int* __restrict__ offU, int Nr, int Nu, int NBr) {
    int bx = blockIdx.x;
    const int* deg = (bx < NBr) ? degR : degU;
    const int* part = (bx < NBr) ? partR : partU;
    int* off = (bx < NBr) ? offR : offU;
    int lb = (bx < NBr) ? bx : bx - NBr;
    int N = (bx < NBr) ? Nr : Nu;
    __shared__ int s[256];
    int t = threadIdx.x;
    int i = lb * 256 + t;
    int v = (i < N) ? deg[i] : 0;
    s[t] = v;
    __syncthreads();
    for (int o = 1; o < 256; o <<= 1) {
        int x = (t >= o) ? s[t - o] : 0;
        __syncthreads();
        s[t] += x;
        __syncthreads();
    }
    if (i < N) off[i] = part[lb] + s[t] - v;
    if (i == N - 1) off[N] = part[lb] + s[t];
}

// fill consumes deg via atomicSub; R side also records eperm (orig edge id)
// and epdst (dst node) per CSR slot for the CSR-ordered edge predictor.
__global__ __launch_bounds__(256)
void fill_kernel(const int* __restrict__ srcR, const int* __restrict__ dstR,
                 const int* __restrict__ srcU, const int* __restrict__ dstU,
                 const int* __restrict__ offR, const int* __restrict__ offU,
                 int* __restrict__ degR, int* __restrict__ degU,
                 int* __restrict__ eidR, int* __restrict__ eidU,
                 int* __restrict__ epermR, int* __restrict__ epdstR,
                 int E, int EB) {
    int bx = blockIdx.x;
    bool isR = bx < EB;
    const int* src = isR ? srcR : srcU;
    const int* dst = isR ? dstR : dstU;
    const int* off = isR ? offR : offU;
    int* deg = isR ? degR : degU;
    int* eid = isR ? eidR : eidU;
    int e = (isR ? bx : bx - EB) * 256 + threadIdx.x;
    if (e < E) {
        int d = dst[e];
        int p = off[d] + atomicSub(&deg[d], 1) - 1;
        eid[p] = src[e];
        if (isR) {
            epermR[p] = e;
            epdstR[p] = d;
        }
    }
}

// ---------------------------------------------------------------------------
// Degree sort (counting sort, 64 buckets) — LDS-privatized histograms.
// Global bucket counters see <=64 atomics per BLOCK, not per node.
// ---------------------------------------------------------------------------
__global__ __launch_bounds__(256)
void dhist_kernel(const int* __restrict__ off_r, const int* __restrict__ off_u,
                  int* __restrict__ bhist, int Nr, int Nu, int NBr) {
    int bx = blockIdx.x;
    bool isR = bx < NBr;
    const int* off = isR ? off_r : off_u;
    int* bh = bhist + (isR ? 0 : 64);
    int N = isR ? Nr : Nu;
    int n = (isR ? bx : bx - NBr) * 256 + threadIdx.x;
    __shared__ int lh[64];
    int t = threadIdx.x;
    if (t < 64) lh[t] = 0;
    __syncthreads();
    if (n < N) {
        int d = off[n + 1] - off[n];
        atomicAdd(&lh[min(d, 63)], 1);
    }
    __syncthreads();
    if (t < 64 && lh[t] > 0) atomicAdd(&bh[t], lh[t]);
}

__global__ __launch_bounds__(64)
void dscan_kernel(const int* __restrict__ bhist, int* __restrict__ boff) {
    __shared__ int s[64];
    int t = threadIdx.x;
    int base = blockIdx.x * 64;
    int v = bhist[base + t];
    s[t] = v;
    __syncthreads();
    for (int o = 1; o < 64; o <<= 1) {
        int x = (t >= o) ? s[t - o] : 0;
        __syncthreads();
        s[t] += x;
        __syncthreads();
    }
    boff[base + t] = s[t] - v;   // exclusive
}

__global__ __launch_bounds__(256)
void dscatter_kernel(const int* __restrict__ off_r, const int* __restrict__ off_u,
                     const int* __restrict__ boff, int* __restrict__ bcnt,
                     int* __restrict__ npr, int* __restrict__ npu,
                     int Nr, int Nu, int NBr) {
    int bx = blockIdx.x;
    bool isR = bx < NBr;
    const int* off = isR ? off_r : off_u;
    const int* bo = boff + (isR ? 0 : 64);
    int* bc = bcnt + (isR ? 0 : 64);
    int* np = isR ? npr : npu;
    int N = isR ? Nr : Nu;
    int n = (isR ? bx : bx - NBr) * 256 + threadIdx.x;
    __shared__ int lh[64];     // local per-bucket count (then rank source)
    __shared__ int lbase[64];  // reserved global base for this block's bucket
    int t = threadIdx.x;
    if (t < 64) lh[t] = 0;
    __syncthreads();
    int b = -1, rank = 0;
    if (n < N) {
        b = min(off[n + 1] - off[n], 63);
        rank = atomicAdd(&lh[b], 1);    // LDS atomic: rank within block
    }
    __syncthreads();
    if (t < 64 && lh[t] > 0) lbase[t] = atomicAdd(&bc[t], lh[t]);  // reserve range
    __syncthreads();
    if (n < N) np[bo[b] + lbase[b] + rank] = n;
}

// ---------------------------------------------------------------------------
// Fused layer: gather-mean + SAGE + BN + ReLU + residual, both node types.
// Nodes processed in degree-sorted order via nodeperm (uniform wave walks).
// ---------------------------------------------------------------------------
__global__ __launch_bounds__(256)
void layer_kernel(const unsigned short* __restrict__ hu_o, const unsigned short* __restrict__ hr_o,
                  unsigned short* __restrict__ hu_n, unsigned short* __restrict__ hr_n,
                  const int* __restrict__ off_r, const int* __restrict__ eid_r,
                  const int* __restrict__ off_u, const int* __restrict__ eid_u,
                  const int* __restrict__ np_r, const int* __restrict__ np_u,
                  int Nu, int Nr, int nbr,
                  const unsigned short* __restrict__ WfR, const float* __restrict__ blR,
                  const float* __restrict__ gR, const float* __restrict__ bR,
                  const float* __restrict__ mR, const float* __restrict__ vR,
                  const unsigned short* __restrict__ WfU, const float* __restrict__ blU,
                  const float* __restrict__ gU, const float* __restrict__ bU,
                  const float* __restrict__ mU, const float* __restrict__ vU) {
    int bx = blockIdx.x;
    const unsigned short* gsrc; const unsigned short* own; unsigned short* outp;
    const int* off; const int* eid; const int* np; const unsigned short* Wf;
    const float *bl, *bg, *bb, *bm, *bv;
    int N, row0;
    if (bx < nbr) {
        gsrc = hu_o; own = hr_o; outp = hr_n; off = off_r; eid = eid_r; np = np_r;
        Wf = WfR; bl = blR; bg = gR; bb = bR; bm = mR; bv = vR;
        N = Nr; row0 = bx * 64;
    } else {
        gsrc = hr_o; own = hu_o; outp = hu_n; off = off_u; eid = eid_u; np = np_u;
        Wf = WfU; bl = blU; bg = gU; bb = bU; bm = mU; bv = vU;
        N = Nu; row0 = (bx - nbr) * 64;
    }

    __shared__ float sc[128], sh[128], bias[128];
    __shared__ int pidx[64];
    int tid = threadIdx.x;
    if (tid < 128) {
        float s = bg[tid] * rsqrtf(bv[tid] + BN_EPS);
        sc[tid] = s;
        sh[tid] = bb[tid] - bm[tid] * s;
        bias[tid] = bl[tid];
    }
    if (tid < 64) {
        int rr = row0 + tid;
        pidx[tid] = (rr < N) ? np[rr] : -1;
    }
    __syncthreads();

    int l = tid & 63, w = tid >> 6, l15 = l & 15, quad = l >> 4;
    int rb = w * 16 + l15;
    int phys = pidx[rb];
    bool rok = (phys >= 0);
    size_t rbase = (size_t)(rok ? phys : 0) * H;
    int s0 = rok ? off[phys] : 0;
    int s1 = rok ? off[phys + 1] : 0;

    // gather-mean into per-lane A-fragment slices (4 chunks x 8 elems)
    float ag[4][8];
    #pragma unroll
    for (int kc = 0; kc < 4; ++kc)
        #pragma unroll
        for (int j = 0; j < 8; ++j) ag[kc][j] = 0.0f;

    for (int i = s0; i < s1; ++i) {
        int s = eid[i];
        const unsigned short* rp = gsrc + (size_t)s * H + quad * 8;
        #pragma unroll
        for (int kc = 0; kc < 4; ++kc) {
            bf16x8 v = *(const bf16x8*)(rp + kc * 32);
            #pragma unroll
            for (int j = 0; j < 8; ++j) ag[kc][j] += bf2f((unsigned short)v[j]);
        }
    }
    float inv = (s1 > s0) ? 1.0f / (float)(s1 - s0) : 0.0f;

    f32x4 acc[8];
    #pragma unroll
    for (int nt = 0; nt < 8; ++nt) acc[nt] = (f32x4){0.f, 0.f, 0.f, 0.f};

    // chunks 0..3: aggregated neighbor mean
    #pragma unroll
    for (int kc = 0; kc < 4; ++kc) {
        bf16x8 a;
        #pragma unroll
        for (int j = 0; j < 8; ++j) a[j] = (short)f2bf(ag[kc][j] * inv);
        #pragma unroll
        for (int nt = 0; nt < 8; ++nt) {
            bf16x8 b = *(const bf16x8*)(Wf + (size_t)((kc * 8 + nt) * 64 + l) * 8);
            acc[nt] = mfma16(a, b, acc[nt]);
        }
    }
    // chunks 4..7: own row (root weight)
    #pragma unroll
    for (int kc = 4; kc < 8; ++kc) {
        bf16x8 a = rok ? *(const bf16x8*)(own + rbase + (kc - 4) * 32 + quad * 8)
                       : (bf16x8){0, 0, 0, 0, 0, 0, 0, 0};
        #pragma unroll
        for (int nt = 0; nt < 8; ++nt) {
            bf16x8 b = *(const bf16x8*)(Wf + (size_t)((kc * 8 + nt) * 64 + l) * 8);
            acc[nt] = mfma16(a, b, acc[nt]);
        }
    }

    // epilogue: bias -> BN -> ReLU -> + residual (bf16), scattered row writes
    #pragma unroll
    for (int reg = 0; reg < 4; ++reg) {
        int crb = w * 16 + quad * 4 + reg;
        int cphys = pidx[crb];
        if (cphys >= 0) {
            #pragma unroll
            for (int nt = 0; nt < 8; ++nt) {
                int col = nt * 16 + l15;
                float g = acc[nt][reg] + bias[col];
                g = g * sc[col] + sh[col];
                float hv = bf2f(own[(size_t)cphys * H + col]);
                outp[(size_t)cphys * H + col] = f2bf(fmaxf(g, 0.0f) + hv);
            }
        }
    }
}

// ---------------------------------------------------------------------------
// Edge predictor via MFMA, processed in CSR (dst-sorted) slot order.
// ---------------------------------------------------------------------------
__global__ __launch_bounds__(256)
void ep_kernel(const unsigned short* __restrict__ hub, const unsigned short* __restrict__ hrb,
               const float* __restrict__ ea,
               const int* __restrict__ slot_src, const int* __restrict__ slot_dst,
               const int* __restrict__ slot_eid,
               const unsigned short* __restrict__ W1f, const float* __restrict__ b1,
               const float* __restrict__ bng, const float* __restrict__ bnb,
               const float* __restrict__ bnm, const float* __restrict__ bnv,
               const unsigned short* __restrict__ W2f, const float* __restrict__ b2,
               const float* __restrict__ W3, const float* __restrict__ b3,
               float* __restrict__ out, int E) {
    __shared__ unsigned short h1s[64][136];
    __shared__ int se[64], de[64], pe[64];
    __shared__ float sc1[128], sh1[128], bi1[128];

    int tid = threadIdx.x;
    int p0 = blockIdx.x * 64;
    if (tid < 64) {
        int p = p0 + tid;
        bool v = (p < E);
        se[tid] = v ? slot_src[p] : 0;
        de[tid] = v ? slot_dst[p] : 0;
        pe[tid] = v ? slot_eid[p] : 0;
    }
    if (tid < 128) {
        float s = bng[tid] * rsqrtf(bnv[tid] + BN_EPS);
        sc1[tid] = s;
        sh1[tid] = bnb[tid] - bnm[tid] * s;
        bi1[tid] = b1[tid];
    }
    __syncthreads();

    int l = tid & 63, w = tid >> 6, l15 = l & 15, quad = l >> 4;
    int arow = w * 16 + l15;
    size_t soff = (size_t)se[arow] * H;
    size_t doff = (size_t)de[arow] * H;
    int eorig = pe[arow];
    bool ev = (p0 + arow < E);

    f32x4 acc[8];
    #pragma unroll
    for (int nt = 0; nt < 8; ++nt) acc[nt] = (f32x4){0.f, 0.f, 0.f, 0.f};

    #pragma unroll
    for (int kc = 0; kc < 9; ++kc) {
        bf16x8 a;
        if (kc < 4) {
            a = *(const bf16x8*)(hub + soff + kc * 32 + quad * 8);
        } else if (kc < 8) {
            a = *(const bf16x8*)(hrb + doff + (kc - 4) * 32 + quad * 8);
        } else {
            a = (bf16x8){0, 0, 0, 0, 0, 0, 0, 0};
            if (quad < 2 && ev) {
                const float* p = ea + (size_t)eorig * 16 + quad * 8;
                float4 v0 = *(const float4*)p;
                float4 v1 = *(const float4*)(p + 4);
                a[0] = (short)f2bf(v0.x); a[1] = (short)f2bf(v0.y);
                a[2] = (short)f2bf(v0.z); a[3] = (short)f2bf(v0.w);
                a[4] = (short)f2bf(v1.x); a[5] = (short)f2bf(v1.y);
                a[6] = (short)f2bf(v1.z); a[7] = (short)f2bf(v1.w);
            }
        }
        #pragma unroll
        for (int nt = 0; nt < 8; ++nt) {
            bf16x8 b = *(const bf16x8*)(W1f + (size_t)((kc * 8 + nt) * 64 + l) * 8);
            acc[nt] = mfma16(a, b, acc[nt]);
        }
    }

    // phase-1 epilogue: bias -> relu -> bn -> bf16 h1s
    #pragma unroll
    for (int nt = 0; nt < 8; ++nt) {
        #pragma unroll
        for (int reg = 0; reg < 4; ++reg) {
            int row = w * 16 + quad * 4 + reg;
            int col = nt * 16 + l15;
            float z = acc[nt][reg] + bi1[col];
            z = fmaxf(z, 0.0f);
            z = z * sc1[col] + sh1[col];
            h1s[row][col] = f2bf(z);
        }
    }
    __syncthreads();

    // phase 2: h2 = relu(h1 @ W2 + b2), K=128, N=64
    f32x4 acc2[4];
    #pragma unroll
    for (int nt = 0; nt < 4; ++nt) acc2[nt] = (f32x4){0.f, 0.f, 0.f, 0.f};
    #pragma unroll
    for (int kc = 0; kc < 4; ++kc) {
        bf16x8 a2 = *(const bf16x8*)&h1s[w * 16 + l15][kc * 32 + quad * 8];
        #pragma unroll
        for (int nt = 0; nt < 4; ++nt) {
            bf16x8 b = *(const bf16x8*)(W2f + (size_t)((kc * 4 + nt) * 64 + l) * 8);
            acc2[nt] = mfma16(a2, b, acc2[nt]);
        }
    }

    // phase 3: per-row dot with W3 via quad shuffle reduction
    float part[4] = {0.f, 0.f, 0.f, 0.f};
    #pragma unroll
    for (int nt = 0; nt < 4; ++nt) {
        int col = nt * 16 + l15;
        float w3v = W3[col];
        float b2v = b2[col];
        #pragma unroll
        for (int reg = 0; reg < 4; ++reg)
            part[reg] += fmaxf(acc2[nt][reg] + b2v, 0.0f) * w3v;
    }
    #pragma unroll
    for (int m = 1; m < 16; m <<= 1) {
        #pragma unroll
        for (int reg = 0; reg < 4; ++reg)
            part[reg] += __shfl_xor(part[reg], m);
    }
    if (l15 < 4) {
        int row = w * 16 + quad * 4 + l15;
        if (p0 + row < E) {
            int eo = pe[row];
            out[eo] = 1.0f / (1.0f + expf(-(part[l15] + b3[0])));
        }
    }
}

// ---------------------------------------------------------------------------
extern "C" void kernel_launch(void* const* d_in, const int* in_sizes, int n_in,
                              void* d_out, int out_size, void* d_ws, size_t ws_size,
                              hipStream_t stream) {
    const float* x_u     = (const float*)d_in[0];
    const float* x_r     = (const float*)d_in[1];
    const float* eattr   = (const float*)d_in[2];
    const int*   ei_ut   = (const int*)d_in[3];
    const int*   ei_ru   = (const int*)d_in[4];
    const float* proj_uW = (const float*)d_in[5];
    const float* proj_ub = (const float*)d_in[6];
    const float* proj_rW = (const float*)d_in[7];
    const float* proj_rb = (const float*)d_in[8];
    const float* sage_Wl = (const float*)d_in[9];
    const float* sage_bl = (const float*)d_in[10];
    const float* sage_Wr = (const float*)d_in[11];
    const float* bn_g    = (const float*)d_in[12];
    const float* bn_b    = (const float*)d_in[13];
    const float* bn_m    = (const float*)d_in[14];
    const float* bn_v    = (const float*)d_in[15];
    const float* ep_W1   = (const float*)d_in[16];
    const float* ep_b1   = (const float*)d_in[17];
    const float* ep_bng  = (const float*)d_in[18];
    const float* ep_bnb  = (const float*)d_in[19];
    const float* ep_bnm  = (const float*)d_in[20];
    const float* ep_bnv  = (const float*)d_in[21];
    const float* ep_W2   = (const float*)d_in[22];
    const float* ep_b2   = (const float*)d_in[23];
    const float* ep_W3   = (const float*)d_in[24];
    const float* ep_b3   = (const float*)d_in[25];

    int Nu = in_sizes[0] / 32;
    int Nr = in_sizes[1] / 32;
    int E  = in_sizes[3] / 2;

    // ---- workspace ----
    unsigned short* us = (unsigned short*)d_ws;
    unsigned short* h0_u = us;   us += (size_t)Nu * H;
    unsigned short* h0_r = us;   us += (size_t)Nr * H;
    unsigned short* h1_u = us;   us += (size_t)Nu * H;
    unsigned short* h1_r = us;   us += (size_t)Nr * H;
    unsigned short* W1f  = us;   us += 36864;
    unsigned short* W2f  = us;   us += 8192;
    unsigned short* puf  = us;   us += 4096;
    unsigned short* prf  = us;   us += 4096;
    unsigned short* sageWf = us; us += 131072;
    int* ip     = (int*)us;
    int* off_r  = ip;  ip += Nr + 1;
    int* off_u  = ip;  ip += Nu + 1;
    int* deg_r  = ip;  ip += Nr;      // deg_r..bcnt contiguous (one memset)
    int* deg_u  = ip;  ip += Nu;
    int* bhist  = ip;  ip += 128;
    int* bcnt   = ip;  ip += 128;
    int* boff   = ip;  ip += 128;
    int* eid_r  = ip;  ip += E;
    int* eid_u  = ip;  ip += E;
    int* eperm_r = ip; ip += E;
    int* epdst_r = ip; ip += E;
    int* np_r   = ip;  ip += Nr;
    int* np_u   = ip;  ip += Nu;
    int* part_r = ip;  ip += 512;
    int* part_u = ip;  ip += 512;

    const int* ut_src = ei_ut;
    const int* ut_dst = ei_ut + E;
    const int* ru_src = ei_ru;
    const int* ru_dst = ei_ru + E;

    int EB  = (E + 255) / 256;
    int NBr = (Nr + 255) / 256;
    int NBu = (Nu + 255) / 256;

    // ---- weight fragments ----
    wfrag_all<<<90, 256, 0, stream>>>(ep_W1, ep_W2, proj_uW, proj_rW,
                                      sage_Wl, sage_Wr,
                                      W1f, W2f, puf, prf, sageWf);

    // ---- CSR build + degree sort ----
    hipMemsetAsync(deg_r, 0, (size_t)(Nr + Nu + 256) * sizeof(int), stream);
    hist_kernel<<<2 * EB, 256, 0, stream>>>(ut_dst, ru_dst, deg_r, deg_u, E, EB);
    scan1_kernel<<<NBr + NBu, 256, 0, stream>>>(deg_r, deg_u, part_r, part_u, Nr, Nu, NBr);
    scan2_kernel<<<2, 512, 0, stream>>>(part_r, part_u, NBr, NBu);
    scan3_kernel<<<NBr + NBu, 256, 0, stream>>>(deg_r, deg_u, part_r, part_u,
                                                off_r, off_u, Nr, Nu, NBr);
    fill_kernel<<<2 * EB, 256, 0, stream>>>(ut_src, ut_dst, ru_src, ru_dst,
                                            off_r, off_u, deg_r, deg_u,
                                            eid_r, eid_u, eperm_r, epdst_r, E, EB);
    dhist_kernel<<<NBr + NBu, 256, 0, stream>>>(off_r, off_u, bhist, Nr, Nu, NBr);
    dscan_kernel<<<2, 64, 0, stream>>>(bhist, boff);
    dscatter_kernel<<<NBr + NBu, 256, 0, stream>>>(off_r, off_u, boff, bcnt,
                                                   np_r, np_u, Nr, Nu, NBr);

    // ---- input projections ----
    int nbu = (Nu + 63) / 64, nbr = (Nr + 63) / 64;
    proj_kernel<<<nbu + nbr, 256, 0, stream>>>(x_u, x_r, puf, proj_ub, prf, proj_rb,
                                               h0_u, h0_r, Nu, Nr, nbu);

    // ---- 2 fused layers (ping-pong h0 -> h1 -> h0) ----
    for (int layer = 0; layer < 2; ++layer) {
        const unsigned short* iu = (layer == 0) ? h0_u : h1_u;
        const unsigned short* ir = (layer == 0) ? h0_r : h1_r;
        unsigned short* ou = (layer == 0) ? h1_u : h0_u;
        unsigned short* orr = (layer == 0) ? h1_r : h0_r;

        const unsigned short* Wf0 = sageWf + ((size_t)layer * 2 + 0) * 32768;
        const unsigned short* Wf1 = sageWf + ((size_t)layer * 2 + 1) * 32768;
        const float* bl0 = sage_bl + ((size_t)layer * 2 + 0) * H;
        const float* bl1 = sage_bl + ((size_t)layer * 2 + 1) * H;
        const float* g0 = bn_g + ((size_t)layer * 2 + 0) * H;   // user BN
        const float* b0 = bn_b + ((size_t)layer * 2 + 0) * H;
        const float* m0 = bn_m + ((size_t)layer * 2 + 0) * H;
        const float* v0 = bn_v + ((size_t)layer * 2 + 0) * H;
        const float* g1 = bn_g + ((size_t)layer * 2 + 1) * H;   // recipient BN
        const float* b1 = bn_b + ((size_t)layer * 2 + 1) * H;
        const float* m1 = bn_m + ((size_t)layer * 2 + 1) * H;
        const float* v1 = bn_v + ((size_t)layer * 2 + 1) * H;

        layer_kernel<<<nbr + nbu, 256, 0, stream>>>(
            iu, ir, ou, orr,
            off_r, eid_r, off_u, eid_u, np_r, np_u,
            Nu, Nr, nbr,
            Wf0, bl0, g1, b1, m1, v1,    // recipient side (edge type 0, BN type 1)
            Wf1, bl1, g0, b0, m0, v0);   // user side (edge type 1, BN type 0)
    }

    ep_kernel<<<(E + 63) / 64, 256, 0, stream>>>(h0_u, h0_r, eattr,
                                                 eid_r, epdst_r, eperm_r,
                                                 W1f, ep_b1,
                                                 ep_bng, ep_bnb, ep_bnm, ep_bnv,
                                                 W2f, ep_b2, ep_W3, ep_b3,
                                                 (float*)d_out, E);
}

// Round 8
// 578.834 us; speedup vs baseline: 2.7662x; 1.0296x over previous
//
#include <hip/hip_runtime.h>
#include <math.h>

#define H 128
#define BN_EPS 1e-5f

typedef __attribute__((ext_vector_type(8))) short bf16x8;
typedef __attribute__((ext_vector_type(4))) float f32x4;

__device__ __forceinline__ unsigned short f2bf(float f) {
    unsigned int u = __float_as_uint(f);
    u += 0x7fffu + ((u >> 16) & 1u);
    return (unsigned short)(u >> 16);
}
__device__ __forceinline__ float bf2f(unsigned short s) {
    return __uint_as_float(((unsigned int)s) << 16);
}
__device__ __forceinline__ f32x4 mfma16(bf16x8 a, bf16x8 b, f32x4 c) {
    return __builtin_amdgcn_mfma_f32_16x16x32_bf16(a, b, c, 0, 0, 0);
}

// ---------------------------------------------------------------------------
// Weight fragment pre-transpose into MFMA B-operand layout (bf16)
// ---------------------------------------------------------------------------
__device__ __forceinline__ void wfrag_one(const float* __restrict__ src,
                                          unsigned short* __restrict__ dst,
                                          int K, int N, int idx) {
    int l = idx & 63;
    int rest = idx >> 6;
    int ntn = N >> 4;
    int nt = rest % ntn;
    int kc = rest / ntn;
    int n = nt * 16 + (l & 15);
    int k0 = kc * 32 + (l >> 4) * 8;
    bf16x8 v;
    #pragma unroll
    for (int j = 0; j < 8; ++j) {
        int k = k0 + j;
        v[j] = (short)((k < K) ? f2bf(src[(size_t)k * N + n]) : 0);
    }
    *(bf16x8*)(dst + (size_t)idx * 8) = v;
}

__global__ __launch_bounds__(256)
void wfrag_all(const float* __restrict__ W1, const float* __restrict__ W2,
               const float* __restrict__ pu, const float* __restrict__ pr,
               const float* __restrict__ Wl, const float* __restrict__ Wr,
               unsigned short* __restrict__ W1f, unsigned short* __restrict__ W2f,
               unsigned short* __restrict__ puf, unsigned short* __restrict__ prf,
               unsigned short* __restrict__ sageWf) {
    int bx = blockIdx.x;
    if (bx < 26) {
        int idx = bx * 256 + threadIdx.x;
        if (idx < 4608)      wfrag_one(W1, W1f, 272, 128, idx);          // K=272 pad 288
        else if (idx < 5632) wfrag_one(W2, W2f, 128, 64, idx - 4608);
        else if (idx < 6144) wfrag_one(pu, puf, 32, 128, idx - 5632);
        else if (idx < 6656) wfrag_one(pr, prf, 32, 128, idx - 6144);
    } else {
        int idx = (bx - 26) * 256 + threadIdx.x;   // < 16384
        int seg = idx >> 11;
        int sub = idx & 2047;
        int lt = seg >> 1;                          // layer*2+type
        int half = seg & 1;                         // 0=Wl, 1=Wr
        const float* src = (half ? Wr : Wl) + (size_t)lt * H * H;
        unsigned short* dst = sageWf + (size_t)lt * 32768 + half * 16384;
        wfrag_one(src, dst, 128, 128, sub);
    }
}

// ---------------------------------------------------------------------------
// Input projection via MFMA: hb = bf16(x @ W + b)
// ---------------------------------------------------------------------------
__global__ __launch_bounds__(256)
void proj_kernel(const float* __restrict__ xu, const float* __restrict__ xr,
                 const unsigned short* __restrict__ puf, const float* __restrict__ bu,
                 const unsigned short* __restrict__ prf, const float* __restrict__ br,
                 unsigned short* __restrict__ hub, unsigned short* __restrict__ hrb,
                 int Nu, int Nr, int nbu) {
    int bx = blockIdx.x;
    const float* x; const unsigned short* Wf; const float* bias;
    unsigned short* hb; int N; int row0;
    if (bx < nbu) { x = xu; Wf = puf; bias = bu; hb = hub; N = Nu; row0 = bx * 64; }
    else          { x = xr; Wf = prf; bias = br; hb = hrb; N = Nr; row0 = (bx - nbu) * 64; }

    int tid = threadIdx.x, l = tid & 63, w = tid >> 6, l15 = l & 15, quad = l >> 4;
    int arow = row0 + w * 16 + l15;

    bf16x8 a = {0, 0, 0, 0, 0, 0, 0, 0};
    if (arow < N) {
        const float* xp = x + (size_t)arow * 32 + quad * 8;
        float4 v0 = *(const float4*)xp;
        float4 v1 = *(const float4*)(xp + 4);
        a[0] = (short)f2bf(v0.x); a[1] = (short)f2bf(v0.y);
        a[2] = (short)f2bf(v0.z); a[3] = (short)f2bf(v0.w);
        a[4] = (short)f2bf(v1.x); a[5] = (short)f2bf(v1.y);
        a[6] = (short)f2bf(v1.z); a[7] = (short)f2bf(v1.w);
    }
    f32x4 acc[8];
    #pragma unroll
    for (int nt = 0; nt < 8; ++nt) {
        bf16x8 b = *(const bf16x8*)(Wf + (size_t)(nt * 64 + l) * 8);
        acc[nt] = mfma16(a, b, (f32x4){0.f, 0.f, 0.f, 0.f});
    }
    #pragma unroll
    for (int reg = 0; reg < 4; ++reg) {
        int row = row0 + w * 16 + quad * 4 + reg;
        if (row < N) {
            #pragma unroll
            for (int nt = 0; nt < 8; ++nt) {
                int col = nt * 16 + l15;
                hb[(size_t)row * H + col] = f2bf(acc[nt][reg] + bias[col]);
            }
        }
    }
}

// ---------------------------------------------------------------------------
// CSR build (both edge types per dispatch)
// ---------------------------------------------------------------------------
__global__ __launch_bounds__(256)
void hist_kernel(const int* __restrict__ dstR, const int* __restrict__ dstU,
                 int* __restrict__ degR, int* __restrict__ degU, int E, int EB) {
    int bx = blockIdx.x;
    const int* dst = (bx < EB) ? dstR : dstU;
    int* deg = (bx < EB) ? degR : degU;
    int e = ((bx < EB) ? bx : bx - EB) * 256 + threadIdx.x;
    if (e < E) atomicAdd(&deg[dst[e]], 1);
}

__global__ __launch_bounds__(256)
void scan1_kernel(const int* __restrict__ degR, const int* __restrict__ degU,
                  int* __restrict__ partR, int* __restrict__ partU, int Nr, int Nu, int NBr) {
    int bx = blockIdx.x;
    const int* deg = (bx < NBr) ? degR : degU;
    int* part = (bx < NBr) ? partR : partU;
    int lb = (bx < NBr) ? bx : bx - NBr;
    int N = (bx < NBr) ? Nr : Nu;
    __shared__ int s[256];
    int t = threadIdx.x;
    int i = lb * 256 + t;
    s[t] = (i < N) ? deg[i] : 0;
    __syncthreads();
    for (int o = 128; o > 0; o >>= 1) {
        if (t < o) s[t] += s[t + o];
        __syncthreads();
    }
    if (t == 0) part[lb] = s[0];
}

__global__ __launch_bounds__(512)
void scan2_kernel(int* __restrict__ partR, int* __restrict__ partU, int nbR, int nbU) {
    int* part = (blockIdx.x == 0) ? partR : partU;
    int nb = (blockIdx.x == 0) ? nbR : nbU;
    __shared__ int s[512];
    int t = threadIdx.x;
    int v = (t < nb) ? part[t] : 0;
    s[t] = v;
    __syncthreads();
    for (int o = 1; o < 512; o <<= 1) {
        int x = (t >= o) ? s[t - o] : 0;
        __syncthreads();
        s[t] += x;
        __syncthreads();
    }
    if (t < nb) part[t] = s[t] - v;   // exclusive
}

__global__ __launch_bounds__(256)
void scan3_kernel(const int* __restrict__ degR, const int* __restrict__ degU,
                  const int* __restrict__ partR, const int* __restrict__ partU,
                  int* __restrict__ offR, int* __restrict__ offU, int Nr, int Nu, int NBr) {
    int bx = blockIdx.x;
    const int* deg = (bx < NBr) ? degR : degU;
    const int* part = (bx < NBr) ? partR : partU;
    int* off = (bx < NBr) ? offR : offU;
    int lb = (bx < NBr) ? bx : bx - NBr;
    int N = (bx < NBr) ? Nr : Nu;
    __shared__ int s[256];
    int t = threadIdx.x;
    int i = lb * 256 + t;
    int v = (i < N) ? deg[i] : 0;
    s[t] = v;
    __syncthreads();
    for (int o = 1; o < 256; o <<= 1) {
        int x = (t >= o) ? s[t - o] : 0;
        __syncthreads();
        s[t] += x;
        __syncthreads();
    }
    if (i < N) off[i] = part[lb] + s[t] - v;
    if (i == N - 1) off[N] = part[lb] + s[t];
}

// fill consumes deg via atomicSub; R side also records eperm (orig edge id)
// and epdst (dst node) per CSR slot for the CSR-ordered edge predictor.
__global__ __launch_bounds__(256)
void fill_kernel(const int* __restrict__ srcR, const int* __restrict__ dstR,
                 const int* __restrict__ srcU, const int* __restrict__ dstU,
                 const int* __restrict__ offR, const int* __restrict__ offU,
                 int* __restrict__ degR, int* __restrict__ degU,
                 int* __restrict__ eidR, int* __restrict__ eidU,
                 int* __restrict__ epermR, int* __restrict__ epdstR,
                 int E, int EB) {
    int bx = blockIdx.x;
    bool isR = bx < EB;
    const int* src = isR ? srcR : srcU;
    const int* dst = isR ? dstR : dstU;
    const int* off = isR ? offR : offU;
    int* deg = isR ? degR : degU;
    int* eid = isR ? eidR : eidU;
    int e = (isR ? bx : bx - EB) * 256 + threadIdx.x;
    if (e < E) {
        int d = dst[e];
        int p = off[d] + atomicSub(&deg[d], 1) - 1;
        eid[p] = src[e];
        if (isR) {
            epermR[p] = e;
            epdstR[p] = d;
        }
    }
}

// ---------------------------------------------------------------------------
// Fused layer: gather-mean + SAGE + BN + ReLU + residual, both node types.
// Own-row fragments preloaded before the CSR walk (overlapped latency).
// ---------------------------------------------------------------------------
__global__ __launch_bounds__(256)
void layer_kernel(const unsigned short* __restrict__ hu_o, const unsigned short* __restrict__ hr_o,
                  unsigned short* __restrict__ hu_n, unsigned short* __restrict__ hr_n,
                  const int* __restrict__ off_r, const int* __restrict__ eid_r,
                  const int* __restrict__ off_u, const int* __restrict__ eid_u,
                  int Nu, int Nr, int nbr,
                  const unsigned short* __restrict__ WfR, const float* __restrict__ blR,
                  const float* __restrict__ gR, const float* __restrict__ bR,
                  const float* __restrict__ mR, const float* __restrict__ vR,
                  const unsigned short* __restrict__ WfU, const float* __restrict__ blU,
                  const float* __restrict__ gU, const float* __restrict__ bU,
                  const float* __restrict__ mU, const float* __restrict__ vU) {
    int bx = blockIdx.x;
    const unsigned short* gsrc; const unsigned short* own; unsigned short* outp;
    const int* off; const int* eid; const unsigned short* Wf;
    const float *bl, *bg, *bb, *bm, *bv;
    int N, row0;
    if (bx < nbr) {
        gsrc = hu_o; own = hr_o; outp = hr_n; off = off_r; eid = eid_r;
        Wf = WfR; bl = blR; bg = gR; bb = bR; bm = mR; bv = vR;
        N = Nr; row0 = bx * 64;
    } else {
        gsrc = hr_o; own = hu_o; outp = hu_n; off = off_u; eid = eid_u;
        Wf = WfU; bl = blU; bg = gU; bb = bU; bm = mU; bv = vU;
        N = Nu; row0 = (bx - nbr) * 64;
    }

    __shared__ float sc[128], sh[128], bias[128];
    int tid = threadIdx.x;
    if (tid < 128) {
        float s = bg[tid] * rsqrtf(bv[tid] + BN_EPS);
        sc[tid] = s;
        sh[tid] = bb[tid] - bm[tid] * s;
        bias[tid] = bl[tid];
    }
    __syncthreads();

    int l = tid & 63, w = tid >> 6, l15 = l & 15, quad = l >> 4;
    int arow = row0 + w * 16 + l15;
    bool rok = (arow < N);
    size_t rbase = (size_t)(rok ? arow : 0) * H;
    int s0 = rok ? off[arow] : 0;
    int s1 = rok ? off[arow + 1] : 0;

    // preload own-row fragments: 4 loads in flight across the whole gather loop
    bf16x8 ownfr[4];
    #pragma unroll
    for (int kc = 0; kc < 4; ++kc)
        ownfr[kc] = *(const bf16x8*)(own + rbase + kc * 32 + quad * 8);

    // gather-mean into per-lane A-fragment slices (4 chunks x 8 elems)
    float ag[4][8];
    #pragma unroll
    for (int kc = 0; kc < 4; ++kc)
        #pragma unroll
        for (int j = 0; j < 8; ++j) ag[kc][j] = 0.0f;

    for (int i = s0; i < s1; ++i) {
        int s = eid[i];
        const unsigned short* rp = gsrc + (size_t)s * H + quad * 8;
        #pragma unroll
        for (int kc = 0; kc < 4; ++kc) {
            bf16x8 v = *(const bf16x8*)(rp + kc * 32);
            #pragma unroll
            for (int j = 0; j < 8; ++j) ag[kc][j] += bf2f((unsigned short)v[j]);
        }
    }
    float inv = (s1 > s0) ? 1.0f / (float)(s1 - s0) : 0.0f;

    f32x4 acc[8];
    #pragma unroll
    for (int nt = 0; nt < 8; ++nt) acc[nt] = (f32x4){0.f, 0.f, 0.f, 0.f};

    // chunks 0..3: aggregated neighbor mean
    #pragma unroll
    for (int kc = 0; kc < 4; ++kc) {
        bf16x8 a;
        #pragma unroll
        for (int j = 0; j < 8; ++j) a[j] = (short)f2bf(ag[kc][j] * inv);
        #pragma unroll
        for (int nt = 0; nt < 8; ++nt) {
            bf16x8 b = *(const bf16x8*)(Wf + (size_t)((kc * 8 + nt) * 64 + l) * 8);
            acc[nt] = mfma16(a, b, acc[nt]);
        }
    }
    // chunks 4..7: own row (root weight), preloaded
    #pragma unroll
    for (int kc = 4; kc < 8; ++kc) {
        #pragma unroll
        for (int nt = 0; nt < 8; ++nt) {
            bf16x8 b = *(const bf16x8*)(Wf + (size_t)((kc * 8 + nt) * 64 + l) * 8);
            acc[nt] = mfma16(ownfr[kc - 4], b, acc[nt]);
        }
    }

    // epilogue: bias -> BN -> ReLU -> + residual (bf16)
    #pragma unroll
    for (int reg = 0; reg < 4; ++reg) {
        int crow = row0 + w * 16 + quad * 4 + reg;
        if (crow < N) {
            #pragma unroll
            for (int nt = 0; nt < 8; ++nt) {
                int col = nt * 16 + l15;
                float g = acc[nt][reg] + bias[col];
                g = g * sc[col] + sh[col];
                float hv = bf2f(own[(size_t)crow * H + col]);
                outp[(size_t)crow * H + col] = f2bf(fmaxf(g, 0.0f) + hv);
            }
        }
    }
}

// ---------------------------------------------------------------------------
// Edge predictor via MFMA, CSR (dst-sorted) slot order, A-fragments fully
// preloaded into registers (9 concurrent global loads per lane).
// ---------------------------------------------------------------------------
__global__ __launch_bounds__(256)
void ep_kernel(const unsigned short* __restrict__ hub, const unsigned short* __restrict__ hrb,
               const float* __restrict__ ea,
               const int* __restrict__ slot_src, const int* __restrict__ slot_dst,
               const int* __restrict__ slot_eid,
               const unsigned short* __restrict__ W1f, const float* __restrict__ b1,
               const float* __restrict__ bng, const float* __restrict__ bnb,
               const float* __restrict__ bnm, const float* __restrict__ bnv,
               const unsigned short* __restrict__ W2f, const float* __restrict__ b2,
               const float* __restrict__ W3, const float* __restrict__ b3,
               float* __restrict__ out, int E) {
    __shared__ unsigned short h1s[64][136];
    __shared__ int se[64], de[64], pe[64];
    __shared__ float sc1[128], sh1[128], bi1[128];

    int tid = threadIdx.x;
    int p0 = blockIdx.x * 64;
    if (tid < 64) {
        int p = p0 + tid;
        bool v = (p < E);
        se[tid] = v ? slot_src[p] : 0;
        de[tid] = v ? slot_dst[p] : 0;
        pe[tid] = v ? slot_eid[p] : 0;
    }
    if (tid < 128) {
        float s = bng[tid] * rsqrtf(bnv[tid] + BN_EPS);
        sc1[tid] = s;
        sh1[tid] = bnb[tid] - bnm[tid] * s;
        bi1[tid] = b1[tid];
    }
    __syncthreads();

    int l = tid & 63, w = tid >> 6, l15 = l & 15, quad = l >> 4;
    int arow = w * 16 + l15;
    size_t soff = (size_t)se[arow] * H;
    size_t doff = (size_t)de[arow] * H;
    int eorig = pe[arow];
    bool ev = (p0 + arow < E);

    // ---- preload ALL phase-1 A-fragments (9 loads in flight per lane) ----
    bf16x8 afr[9];
    #pragma unroll
    for (int kc = 0; kc < 4; ++kc)
        afr[kc] = *(const bf16x8*)(hub + soff + kc * 32 + quad * 8);
    #pragma unroll
    for (int kc = 0; kc < 4; ++kc)
        afr[4 + kc] = *(const bf16x8*)(hrb + doff + kc * 32 + quad * 8);
    {
        bf16x8 a = {0, 0, 0, 0, 0, 0, 0, 0};
        if (quad < 2 && ev) {
            const float* p = ea + (size_t)eorig * 16 + quad * 8;
            float4 v0 = *(const float4*)p;
            float4 v1 = *(const float4*)(p + 4);
            a[0] = (short)f2bf(v0.x); a[1] = (short)f2bf(v0.y);
            a[2] = (short)f2bf(v0.z); a[3] = (short)f2bf(v0.w);
            a[4] = (short)f2bf(v1.x); a[5] = (short)f2bf(v1.y);
            a[6] = (short)f2bf(v1.z); a[7] = (short)f2bf(v1.w);
        }
        afr[8] = a;
    }

    f32x4 acc[8];
    #pragma unroll
    for (int nt = 0; nt < 8; ++nt) acc[nt] = (f32x4){0.f, 0.f, 0.f, 0.f};

    #pragma unroll
    for (int kc = 0; kc < 9; ++kc) {
        #pragma unroll
        for (int nt = 0; nt < 8; ++nt) {
            bf16x8 b = *(const bf16x8*)(W1f + (size_t)((kc * 8 + nt) * 64 + l) * 8);
            acc[nt] = mfma16(afr[kc], b, acc[nt]);
        }
    }

    // phase-1 epilogue: bias -> relu -> bn -> bf16 h1s
    #pragma unroll
    for (int nt = 0; nt < 8; ++nt) {
        #pragma unroll
        for (int reg = 0; reg < 4; ++reg) {
            int row = w * 16 + quad * 4 + reg;
            int col = nt * 16 + l15;
            float z = acc[nt][reg] + bi1[col];
            z = fmaxf(z, 0.0f);
            z = z * sc1[col] + sh1[col];
            h1s[row][col] = f2bf(z);
        }
    }
    __syncthreads();

    // phase 2: h2 = relu(h1 @ W2 + b2), K=128, N=64
    f32x4 acc2[4];
    #pragma unroll
    for (int nt = 0; nt < 4; ++nt) acc2[nt] = (f32x4){0.f, 0.f, 0.f, 0.f};
    #pragma unroll
    for (int kc = 0; kc < 4; ++kc) {
        bf16x8 a2 = *(const bf16x8*)&h1s[w * 16 + l15][kc * 32 + quad * 8];
        #pragma unroll
        for (int nt = 0; nt < 4; ++nt) {
            bf16x8 b = *(const bf16x8*)(W2f + (size_t)((kc * 4 + nt) * 64 + l) * 8);
            acc2[nt] = mfma16(a2, b, acc2[nt]);
        }
    }

    // phase 3: per-row dot with W3 via quad shuffle reduction
    float part[4] = {0.f, 0.f, 0.f, 0.f};
    #pragma unroll
    for (int nt = 0; nt < 4; ++nt) {
        int col = nt * 16 + l15;
        float w3v = W3[col];
        float b2v = b2[col];
        #pragma unroll
        for (int reg = 0; reg < 4; ++reg)
            part[reg] += fmaxf(acc2[nt][reg] + b2v, 0.0f) * w3v;
    }
    #pragma unroll
    for (int m = 1; m < 16; m <<= 1) {
        #pragma unroll
        for (int reg = 0; reg < 4; ++reg)
            part[reg] += __shfl_xor(part[reg], m);
    }
    if (l15 < 4) {
        int row = w * 16 + quad * 4 + l15;
        if (p0 + row < E) {
            int eo = pe[row];
            out[eo] = 1.0f / (1.0f + expf(-(part[l15] + b3[0])));
        }
    }
}

// ---------------------------------------------------------------------------
extern "C" void kernel_launch(void* const* d_in, const int* in_sizes, int n_in,
                              void* d_out, int out_size, void* d_ws, size_t ws_size,
                              hipStream_t stream) {
    const float* x_u     = (const float*)d_in[0];
    const float* x_r     = (const float*)d_in[1];
    const float* eattr   = (const float*)d_in[2];
    const int*   ei_ut   = (const int*)d_in[3];
    const int*   ei_ru   = (const int*)d_in[4];
    const float* proj_uW = (const float*)d_in[5];
    const float* proj_ub = (const float*)d_in[6];
    const float* proj_rW = (const float*)d_in[7];
    const float* proj_rb = (const float*)d_in[8];
    const float* sage_Wl = (const float*)d_in[9];
    const float* sage_bl = (const float*)d_in[10];
    const float* sage_Wr = (const float*)d_in[11];
    const float* bn_g    = (const float*)d_in[12];
    const float* bn_b    = (const float*)d_in[13];
    const float* bn_m    = (const float*)d_in[14];
    const float* bn_v    = (const float*)d_in[15];
    const float* ep_W1   = (const float*)d_in[16];
    const float* ep_b1   = (const float*)d_in[17];
    const float* ep_bng  = (const float*)d_in[18];
    const float* ep_bnb  = (const float*)d_in[19];
    const float* ep_bnm  = (const float*)d_in[20];
    const float* ep_bnv  = (const float*)d_in[21];
    const float* ep_W2   = (const float*)d_in[22];
    const float* ep_b2   = (const float*)d_in[23];
    const float* ep_W3   = (const float*)d_in[24];
    const float* ep_b3   = (const float*)d_in[25];

    int Nu = in_sizes[0] / 32;
    int Nr = in_sizes[1] / 32;
    int E  = in_sizes[3] / 2;

    // ---- workspace ----
    unsigned short* us = (unsigned short*)d_ws;
    unsigned short* h0_u = us;   us += (size_t)Nu * H;
    unsigned short* h0_r = us;   us += (size_t)Nr * H;
    unsigned short* h1_u = us;   us += (size_t)Nu * H;
    unsigned short* h1_r = us;   us += (size_t)Nr * H;
    unsigned short* W1f  = us;   us += 36864;
    unsigned short* W2f  = us;   us += 8192;
    unsigned short* puf  = us;   us += 4096;
    unsigned short* prf  = us;   us += 4096;
    unsigned short* sageWf = us; us += 131072;
    int* ip     = (int*)us;
    int* off_r  = ip;  ip += Nr + 1;
    int* off_u  = ip;  ip += Nu + 1;
    int* deg_r  = ip;  ip += Nr;      // deg_r/deg_u contiguous (one memset)
    int* deg_u  = ip;  ip += Nu;
    int* eid_r  = ip;  ip += E;
    int* eid_u  = ip;  ip += E;
    int* eperm_r = ip; ip += E;
    int* epdst_r = ip; ip += E;
    int* part_r = ip;  ip += 512;
    int* part_u = ip;  ip += 512;

    const int* ut_src = ei_ut;
    const int* ut_dst = ei_ut + E;
    const int* ru_src = ei_ru;
    const int* ru_dst = ei_ru + E;

    int EB  = (E + 255) / 256;
    int NBr = (Nr + 255) / 256;
    int NBu = (Nu + 255) / 256;

    // ---- weight fragments ----
    wfrag_all<<<90, 256, 0, stream>>>(ep_W1, ep_W2, proj_uW, proj_rW,
                                      sage_Wl, sage_Wr,
                                      W1f, W2f, puf, prf, sageWf);

    // ---- CSR build ----
    hipMemsetAsync(deg_r, 0, (size_t)(Nr + Nu) * sizeof(int), stream);
    hist_kernel<<<2 * EB, 256, 0, stream>>>(ut_dst, ru_dst, deg_r, deg_u, E, EB);
    scan1_kernel<<<NBr + NBu, 256, 0, stream>>>(deg_r, deg_u, part_r, part_u, Nr, Nu, NBr);
    scan2_kernel<<<2, 512, 0, stream>>>(part_r, part_u, NBr, NBu);
    scan3_kernel<<<NBr + NBu, 256, 0, stream>>>(deg_r, deg_u, part_r, part_u,
                                                off_r, off_u, Nr, Nu, NBr);
    fill_kernel<<<2 * EB, 256, 0, stream>>>(ut_src, ut_dst, ru_src, ru_dst,
                                            off_r, off_u, deg_r, deg_u,
                                            eid_r, eid_u, eperm_r, epdst_r, E, EB);

    // ---- input projections ----
    int nbu = (Nu + 63) / 64, nbr = (Nr + 63) / 64;
    proj_kernel<<<nbu + nbr, 256, 0, stream>>>(x_u, x_r, puf, proj_ub, prf, proj_rb,
                                               h0_u, h0_r, Nu, Nr, nbu);

    // ---- 2 fused layers (ping-pong h0 -> h1 -> h0) ----
    for (int layer = 0; layer < 2; ++layer) {
        const unsigned short* iu = (layer == 0) ? h0_u : h1_u;
        const unsigned short* ir = (layer == 0) ? h0_r : h1_r;
        unsigned short* ou = (layer == 0) ? h1_u : h0_u;
        unsigned short* orr = (layer == 0) ? h1_r : h0_r;

        const unsigned short* Wf0 = sageWf + ((size_t)layer * 2 + 0) * 32768;
        const unsigned short* Wf1 = sageWf + ((size_t)layer * 2 + 1) * 32768;
        const float* bl0 = sage_bl + ((size_t)layer * 2 + 0) * H;
        const float* bl1 = sage_bl + ((size_t)layer * 2 + 1) * H;
        const float* g0 = bn_g + ((size_t)layer * 2 + 0) * H;   // user BN
        const float* b0 = bn_b + ((size_t)layer * 2 + 0) * H;
        const float* m0 = bn_m + ((size_t)layer * 2 + 0) * H;
        const float* v0 = bn_v + ((size_t)layer * 2 + 0) * H;
        const float* g1 = bn_g + ((size_t)layer * 2 + 1) * H;   // recipient BN
        const float* b1 = bn_b + ((size_t)layer * 2 + 1) * H;
        const float* m1 = bn_m + ((size_t)layer * 2 + 1) * H;
        const float* v1 = bn_v + ((size_t)layer * 2 + 1) * H;

        layer_kernel<<<nbr + nbu, 256, 0, stream>>>(
            iu, ir, ou, orr,
            off_r, eid_r, off_u, eid_u,
            Nu, Nr, nbr,
            Wf0, bl0, g1, b1, m1, v1,    // recipient side (edge type 0, BN type 1)
            Wf1, bl1, g0, b0, m0, v0);   // user side (edge type 1, BN type 0)
    }

    ep_kernel<<<(E + 63) / 64, 256, 0, stream>>>(h0_u, h0_r, eattr,
                                                 eid_r, epdst_r, eperm_r,
                                                 W1f, ep_b1,
                                                 ep_bng, ep_bnb, ep_bnm, ep_bnv,
                                                 W2f, ep_b2, ep_W3, ep_b3,
                                                 (float*)d_out, E);
}

// Round 9
// 553.813 us; speedup vs baseline: 2.8912x; 1.0452x over previous
//
#include <hip/hip_runtime.h>
#include <math.h>

#define H 128
#define BN_EPS 1e-5f

typedef __attribute__((ext_vector_type(8))) short bf16x8;
typedef __attribute__((ext_vector_type(4))) float f32x4;

__device__ __forceinline__ unsigned short f2bf(float f) {
    unsigned int u = __float_as_uint(f);
    u += 0x7fffu + ((u >> 16) & 1u);
    return (unsigned short)(u >> 16);
}
__device__ __forceinline__ float bf2f(unsigned short s) {
    return __uint_as_float(((unsigned int)s) << 16);
}
__device__ __forceinline__ f32x4 mfma16(bf16x8 a, bf16x8 b, f32x4 c) {
    return __builtin_amdgcn_mfma_f32_16x16x32_bf16(a, b, c, 0, 0, 0);
}

// ---------------------------------------------------------------------------
// Weight fragment pre-transpose into MFMA B-operand layout (bf16)
// ---------------------------------------------------------------------------
__device__ __forceinline__ void wfrag_one(const float* __restrict__ src,
                                          unsigned short* __restrict__ dst,
                                          int K, int N, int idx) {
    int l = idx & 63;
    int rest = idx >> 6;
    int ntn = N >> 4;
    int nt = rest % ntn;
    int kc = rest / ntn;
    int n = nt * 16 + (l & 15);
    int k0 = kc * 32 + (l >> 4) * 8;
    bf16x8 v;
    #pragma unroll
    for (int j = 0; j < 8; ++j) {
        int k = k0 + j;
        v[j] = (short)((k < K) ? f2bf(src[(size_t)k * N + n]) : 0);
    }
    *(bf16x8*)(dst + (size_t)idx * 8) = v;
}

__global__ __launch_bounds__(256)
void wfrag_all(const float* __restrict__ W1, const float* __restrict__ W2,
               const float* __restrict__ pu, const float* __restrict__ pr,
               const float* __restrict__ Wl, const float* __restrict__ Wr,
               unsigned short* __restrict__ W1f, unsigned short* __restrict__ W2f,
               unsigned short* __restrict__ puf, unsigned short* __restrict__ prf,
               unsigned short* __restrict__ sageWf) {
    int bx = blockIdx.x;
    if (bx < 26) {
        int idx = bx * 256 + threadIdx.x;
        if (idx < 4608)      wfrag_one(W1, W1f, 272, 128, idx);          // K=272 pad 288
        else if (idx < 5632) wfrag_one(W2, W2f, 128, 64, idx - 4608);
        else if (idx < 6144) wfrag_one(pu, puf, 32, 128, idx - 5632);
        else if (idx < 6656) wfrag_one(pr, prf, 32, 128, idx - 6144);
    } else {
        int idx = (bx - 26) * 256 + threadIdx.x;   // < 16384
        int seg = idx >> 11;
        int sub = idx & 2047;
        int lt = seg >> 1;                          // layer*2+type
        int half = seg & 1;                         // 0=Wl, 1=Wr
        const float* src = (half ? Wr : Wl) + (size_t)lt * H * H;
        unsigned short* dst = sageWf + (size_t)lt * 32768 + half * 16384;
        wfrag_one(src, dst, 128, 128, sub);
    }
}

// ---------------------------------------------------------------------------
// Input projection via MFMA: hb = bf16(x @ W + b)
// ---------------------------------------------------------------------------
__global__ __launch_bounds__(256)
void proj_kernel(const float* __restrict__ xu, const float* __restrict__ xr,
                 const unsigned short* __restrict__ puf, const float* __restrict__ bu,
                 const unsigned short* __restrict__ prf, const float* __restrict__ br,
                 unsigned short* __restrict__ hub, unsigned short* __restrict__ hrb,
                 int Nu, int Nr, int nbu) {
    int bx = blockIdx.x;
    const float* x; const unsigned short* Wf; const float* bias;
    unsigned short* hb; int N; int row0;
    if (bx < nbu) { x = xu; Wf = puf; bias = bu; hb = hub; N = Nu; row0 = bx * 64; }
    else          { x = xr; Wf = prf; bias = br; hb = hrb; N = Nr; row0 = (bx - nbu) * 64; }

    int tid = threadIdx.x, l = tid & 63, w = tid >> 6, l15 = l & 15, quad = l >> 4;
    int arow = row0 + w * 16 + l15;

    bf16x8 a = {0, 0, 0, 0, 0, 0, 0, 0};
    if (arow < N) {
        const float* xp = x + (size_t)arow * 32 + quad * 8;
        float4 v0 = *(const float4*)xp;
        float4 v1 = *(const float4*)(xp + 4);
        a[0] = (short)f2bf(v0.x); a[1] = (short)f2bf(v0.y);
        a[2] = (short)f2bf(v0.z); a[3] = (short)f2bf(v0.w);
        a[4] = (short)f2bf(v1.x); a[5] = (short)f2bf(v1.y);
        a[6] = (short)f2bf(v1.z); a[7] = (short)f2bf(v1.w);
    }
    f32x4 acc[8];
    #pragma unroll
    for (int nt = 0; nt < 8; ++nt) {
        bf16x8 b = *(const bf16x8*)(Wf + (size_t)(nt * 64 + l) * 8);
        acc[nt] = mfma16(a, b, (f32x4){0.f, 0.f, 0.f, 0.f});
    }
    #pragma unroll
    for (int reg = 0; reg < 4; ++reg) {
        int row = row0 + w * 16 + quad * 4 + reg;
        if (row < N) {
            #pragma unroll
            for (int nt = 0; nt < 8; ++nt) {
                int col = nt * 16 + l15;
                hb[(size_t)row * H + col] = f2bf(acc[nt][reg] + bias[col]);
            }
        }
    }
}

// ---------------------------------------------------------------------------
// CSR build (both edge types per dispatch)
// ---------------------------------------------------------------------------
__global__ __launch_bounds__(256)
void hist_kernel(const int* __restrict__ dstR, const int* __restrict__ dstU,
                 int* __restrict__ degR, int* __restrict__ degU, int E, int EB) {
    int bx = blockIdx.x;
    const int* dst = (bx < EB) ? dstR : dstU;
    int* deg = (bx < EB) ? degR : degU;
    int e = ((bx < EB) ? bx : bx - EB) * 256 + threadIdx.x;
    if (e < E) atomicAdd(&deg[dst[e]], 1);
}

__global__ __launch_bounds__(256)
void scan1_kernel(const int* __restrict__ degR, const int* __restrict__ degU,
                  int* __restrict__ partR, int* __restrict__ partU, int Nr, int Nu, int NBr) {
    int bx = blockIdx.x;
    const int* deg = (bx < NBr) ? degR : degU;
    int* part = (bx < NBr) ? partR : partU;
    int lb = (bx < NBr) ? bx : bx - NBr;
    int N = (bx < NBr) ? Nr : Nu;
    __shared__ int s[256];
    int t = threadIdx.x;
    int i = lb * 256 + t;
    s[t] = (i < N) ? deg[i] : 0;
    __syncthreads();
    for (int o = 128; o > 0; o >>= 1) {
        if (t < o) s[t] += s[t + o];
        __syncthreads();
    }
    if (t == 0) part[lb] = s[0];
}

// scan3 now also computes the global prefix of raw block sums itself
// (one fewer dispatch: scan2 eliminated)
__global__ __launch_bounds__(256)
void scan3_kernel(const int* __restrict__ degR, const int* __restrict__ degU,
                  const int* __restrict__ partR, const int* __restrict__ partU,
                  int* __restrict__ offR, int* __restrict__ offU, int Nr, int Nu, int NBr) {
    int bx = blockIdx.x;
    const int* deg = (bx < NBr) ? degR : degU;
    const int* part = (bx < NBr) ? partR : partU;
    int* off = (bx < NBr) ? offR : offU;
    int lb = (bx < NBr) ? bx : bx - NBr;
    int N = (bx < NBr) ? Nr : Nu;
    __shared__ int s[256];
    __shared__ int ps[256];
    int t = threadIdx.x;

    // prefix over raw block sums part[0..lb-1]  (block count <= 512)
    int pv = 0;
    if (t < lb) pv += part[t];
    if (t + 256 < lb) pv += part[t + 256];
    ps[t] = pv;
    __syncthreads();
    for (int o = 128; o > 0; o >>= 1) {
        if (t < o) ps[t] += ps[t + o];
        __syncthreads();
    }
    int pref = ps[0];

    int i = lb * 256 + t;
    int v = (i < N) ? deg[i] : 0;
    s[t] = v;
    __syncthreads();
    for (int o = 1; o < 256; o <<= 1) {
        int x = (t >= o) ? s[t - o] : 0;
        __syncthreads();
        s[t] += x;
        __syncthreads();
    }
    if (i < N) off[i] = pref + s[t] - v;
    if (i == N - 1) off[N] = pref + s[t];
}

// fill consumes deg via atomicSub; R side also records eperm (orig edge id)
// and epdst (dst node) per CSR slot for the CSR-ordered edge predictor.
__global__ __launch_bounds__(256)
void fill_kernel(const int* __restrict__ srcR, const int* __restrict__ dstR,
                 const int* __restrict__ srcU, const int* __restrict__ dstU,
                 const int* __restrict__ offR, const int* __restrict__ offU,
                 int* __restrict__ degR, int* __restrict__ degU,
                 int* __restrict__ eidR, int* __restrict__ eidU,
                 int* __restrict__ epermR, int* __restrict__ epdstR,
                 int E, int EB) {
    int bx = blockIdx.x;
    bool isR = bx < EB;
    const int* src = isR ? srcR : srcU;
    const int* dst = isR ? dstR : dstU;
    const int* off = isR ? offR : offU;
    int* deg = isR ? degR : degU;
    int* eid = isR ? eidR : eidU;
    int e = (isR ? bx : bx - EB) * 256 + threadIdx.x;
    if (e < E) {
        int d = dst[e];
        int p = off[d] + atomicSub(&deg[d], 1) - 1;
        eid[p] = src[e];
        if (isR) {
            epermR[p] = e;
            epdstR[p] = d;
        }
    }
}

// ---------------------------------------------------------------------------
// Fused layer: gather-mean + SAGE + BN + ReLU + residual, both node types.
// In-block degree sort (wave-0 bitonic over 64 rows) gives each wave
// uniform-length CSR walks -> full-MLP gather issue. Per-row arithmetic
// is bit-identical (rows of an MFMA tile don't mix).
// ---------------------------------------------------------------------------
__global__ __launch_bounds__(256)
void layer_kernel(const unsigned short* __restrict__ hu_o, const unsigned short* __restrict__ hr_o,
                  unsigned short* __restrict__ hu_n, unsigned short* __restrict__ hr_n,
                  const int* __restrict__ off_r, const int* __restrict__ eid_r,
                  const int* __restrict__ off_u, const int* __restrict__ eid_u,
                  int Nu, int Nr, int nbr,
                  const unsigned short* __restrict__ WfR, const float* __restrict__ blR,
                  const float* __restrict__ gR, const float* __restrict__ bR,
                  const float* __restrict__ mR, const float* __restrict__ vR,
                  const unsigned short* __restrict__ WfU, const float* __restrict__ blU,
                  const float* __restrict__ gU, const float* __restrict__ bU,
                  const float* __restrict__ mU, const float* __restrict__ vU) {
    int bx = blockIdx.x;
    const unsigned short* gsrc; const unsigned short* own; unsigned short* outp;
    const int* off; const int* eid; const unsigned short* Wf;
    const float *bl, *bg, *bb, *bm, *bv;
    int N, row0;
    if (bx < nbr) {
        gsrc = hu_o; own = hr_o; outp = hr_n; off = off_r; eid = eid_r;
        Wf = WfR; bl = blR; bg = gR; bb = bR; bm = mR; bv = vR;
        N = Nr; row0 = bx * 64;
    } else {
        gsrc = hr_o; own = hu_o; outp = hu_n; off = off_u; eid = eid_u;
        Wf = WfU; bl = blU; bg = gU; bb = bU; bm = mU; bv = vU;
        N = Nu; row0 = (bx - nbr) * 64;
    }

    __shared__ float sc[128], sh[128], bias[128];
    __shared__ int perm[64];
    int tid = threadIdx.x;
    if (tid < 128) {
        float s = bg[tid] * rsqrtf(bv[tid] + BN_EPS);
        sc[tid] = s;
        sh[tid] = bb[tid] - bm[tid] * s;
        bias[tid] = bl[tid];
    }
    if (tid < 64) {
        // wave-0 bitonic sort of (deg, rowlocal) keys, ascending by degree
        int rr = row0 + tid;
        int dg = (rr < N) ? (off[rr + 1] - off[rr]) : 0;
        int key = (min(dg, 255) << 8) | tid;
        for (int k = 2; k <= 64; k <<= 1) {
            for (int j = k >> 1; j > 0; j >>= 1) {
                int p = __shfl_xor(key, j);
                bool keepmin = (((tid & j) == 0) == ((tid & k) == 0));
                key = keepmin ? (key < p ? key : p) : (key > p ? key : p);
            }
        }
        perm[tid] = key & 255;
    }
    __syncthreads();

    int l = tid & 63, w = tid >> 6, l15 = l & 15, quad = l >> 4;
    int rloc = perm[w * 16 + l15];
    int arow = row0 + rloc;
    bool rok = (arow < N);
    size_t rbase = (size_t)(rok ? arow : 0) * H;
    int s0 = rok ? off[arow] : 0;
    int s1 = rok ? off[arow + 1] : 0;

    // preload own-row fragments (in flight across the whole gather loop)
    bf16x8 ownfr[4];
    #pragma unroll
    for (int kc = 0; kc < 4; ++kc)
        ownfr[kc] = *(const bf16x8*)(own + rbase + kc * 32 + quad * 8);

    // gather-mean into per-lane A-fragment slices (4 chunks x 8 elems)
    float ag[4][8];
    #pragma unroll
    for (int kc = 0; kc < 4; ++kc)
        #pragma unroll
        for (int j = 0; j < 8; ++j) ag[kc][j] = 0.0f;

    for (int i = s0; i < s1; ++i) {
        int s = eid[i];
        const unsigned short* rp = gsrc + (size_t)s * H + quad * 8;
        #pragma unroll
        for (int kc = 0; kc < 4; ++kc) {
            bf16x8 v = *(const bf16x8*)(rp + kc * 32);
            #pragma unroll
            for (int j = 0; j < 8; ++j) ag[kc][j] += bf2f((unsigned short)v[j]);
        }
    }
    float inv = (s1 > s0) ? 1.0f / (float)(s1 - s0) : 0.0f;

    f32x4 acc[8];
    #pragma unroll
    for (int nt = 0; nt < 8; ++nt) acc[nt] = (f32x4){0.f, 0.f, 0.f, 0.f};

    // chunks 0..3: aggregated neighbor mean
    #pragma unroll
    for (int kc = 0; kc < 4; ++kc) {
        bf16x8 a;
        #pragma unroll
        for (int j = 0; j < 8; ++j) a[j] = (short)f2bf(ag[kc][j] * inv);
        #pragma unroll
        for (int nt = 0; nt < 8; ++nt) {
            bf16x8 b = *(const bf16x8*)(Wf + (size_t)((kc * 8 + nt) * 64 + l) * 8);
            acc[nt] = mfma16(a, b, acc[nt]);
        }
    }
    // chunks 4..7: own row (root weight), preloaded
    #pragma unroll
    for (int kc = 4; kc < 8; ++kc) {
        #pragma unroll
        for (int nt = 0; nt < 8; ++nt) {
            bf16x8 b = *(const bf16x8*)(Wf + (size_t)((kc * 8 + nt) * 64 + l) * 8);
            acc[nt] = mfma16(ownfr[kc - 4], b, acc[nt]);
        }
    }

    // epilogue: bias -> BN -> ReLU -> + residual (bf16), permuted rows
    #pragma unroll
    for (int reg = 0; reg < 4; ++reg) {
        int crow = row0 + perm[w * 16 + quad * 4 + reg];
        if (crow < N) {
            #pragma unroll
            for (int nt = 0; nt < 8; ++nt) {
                int col = nt * 16 + l15;
                float g = acc[nt][reg] + bias[col];
                g = g * sc[col] + sh[col];
                float hv = bf2f(own[(size_t)crow * H + col]);
                outp[(size_t)crow * H + col] = f2bf(fmaxf(g, 0.0f) + hv);
            }
        }
    }
}

// ---------------------------------------------------------------------------
// Edge predictor via MFMA, CSR (dst-sorted) slot order, A-fragments fully
// preloaded into registers (9 concurrent global loads per lane).
// ---------------------------------------------------------------------------
__global__ __launch_bounds__(256)
void ep_kernel(const unsigned short* __restrict__ hub, const unsigned short* __restrict__ hrb,
               const float* __restrict__ ea,
               const int* __restrict__ slot_src, const int* __restrict__ slot_dst,
               const int* __restrict__ slot_eid,
               const unsigned short* __restrict__ W1f, const float* __restrict__ b1,
               const float* __restrict__ bng, const float* __restrict__ bnb,
               const float* __restrict__ bnm, const float* __restrict__ bnv,
               const unsigned short* __restrict__ W2f, const float* __restrict__ b2,
               const float* __restrict__ W3, const float* __restrict__ b3,
               float* __restrict__ out, int E) {
    __shared__ unsigned short h1s[64][136];
    __shared__ int se[64], de[64], pe[64];
    __shared__ float sc1[128], sh1[128], bi1[128];

    int tid = threadIdx.x;
    int p0 = blockIdx.x * 64;
    if (tid < 64) {
        int p = p0 + tid;
        bool v = (p < E);
        se[tid] = v ? slot_src[p] : 0;
        de[tid] = v ? slot_dst[p] : 0;
        pe[tid] = v ? slot_eid[p] : 0;
    }
    if (tid < 128) {
        float s = bng[tid] * rsqrtf(bnv[tid] + BN_EPS);
        sc1[tid] = s;
        sh1[tid] = bnb[tid] - bnm[tid] * s;
        bi1[tid] = b1[tid];
    }
    __syncthreads();

    int l = tid & 63, w = tid >> 6, l15 = l & 15, quad = l >> 4;
    int arow = w * 16 + l15;
    size_t soff = (size_t)se[arow] * H;
    size_t doff = (size_t)de[arow] * H;
    int eorig = pe[arow];
    bool ev = (p0 + arow < E);

    // ---- preload ALL phase-1 A-fragments (9 loads in flight per lane) ----
    bf16x8 afr[9];
    #pragma unroll
    for (int kc = 0; kc < 4; ++kc)
        afr[kc] = *(const bf16x8*)(hub + soff + kc * 32 + quad * 8);
    #pragma unroll
    for (int kc = 0; kc < 4; ++kc)
        afr[4 + kc] = *(const bf16x8*)(hrb + doff + kc * 32 + quad * 8);
    {
        bf16x8 a = {0, 0, 0, 0, 0, 0, 0, 0};
        if (quad < 2 && ev) {
            const float* p = ea + (size_t)eorig * 16 + quad * 8;
            float4 v0 = *(const float4*)p;
            float4 v1 = *(const float4*)(p + 4);
            a[0] = (short)f2bf(v0.x); a[1] = (short)f2bf(v0.y);
            a[2] = (short)f2bf(v0.z); a[3] = (short)f2bf(v0.w);
            a[4] = (short)f2bf(v1.x); a[5] = (short)f2bf(v1.y);
            a[6] = (short)f2bf(v1.z); a[7] = (short)f2bf(v1.w);
        }
        afr[8] = a;
    }

    f32x4 acc[8];
    #pragma unroll
    for (int nt = 0; nt < 8; ++nt) acc[nt] = (f32x4){0.f, 0.f, 0.f, 0.f};

    #pragma unroll
    for (int kc = 0; kc < 9; ++kc) {
        #pragma unroll
        for (int nt = 0; nt < 8; ++nt) {
            bf16x8 b = *(const bf16x8*)(W1f + (size_t)((kc * 8 + nt) * 64 + l) * 8);
            acc[nt] = mfma16(afr[kc], b, acc[nt]);
        }
    }

    // phase-1 epilogue: bias -> relu -> bn -> bf16 h1s
    #pragma unroll
    for (int nt = 0; nt < 8; ++nt) {
        #pragma unroll
        for (int reg = 0; reg < 4; ++reg) {
            int row = w * 16 + quad * 4 + reg;
            int col = nt * 16 + l15;
            float z = acc[nt][reg] + bi1[col];
            z = fmaxf(z, 0.0f);
            z = z * sc1[col] + sh1[col];
            h1s[row][col] = f2bf(z);
        }
    }
    __syncthreads();

    // phase 2: h2 = relu(h1 @ W2 + b2), K=128, N=64
    f32x4 acc2[4];
    #pragma unroll
    for (int nt = 0; nt < 4; ++nt) acc2[nt] = (f32x4){0.f, 0.f, 0.f, 0.f};
    #pragma unroll
    for (int kc = 0; kc < 4; ++kc) {
        bf16x8 a2 = *(const bf16x8*)&h1s[w * 16 + l15][kc * 32 + quad * 8];
        #pragma unroll
        for (int nt = 0; nt < 4; ++nt) {
            bf16x8 b = *(const bf16x8*)(W2f + (size_t)((kc * 4 + nt) * 64 + l) * 8);
            acc2[nt] = mfma16(a2, b, acc2[nt]);
        }
    }

    // phase 3: per-row dot with W3 via quad shuffle reduction
    float part[4] = {0.f, 0.f, 0.f, 0.f};
    #pragma unroll
    for (int nt = 0; nt < 4; ++nt) {
        int col = nt * 16 + l15;
        float w3v = W3[col];
        float b2v = b2[col];
        #pragma unroll
        for (int reg = 0; reg < 4; ++reg)
            part[reg] += fmaxf(acc2[nt][reg] + b2v, 0.0f) * w3v;
    }
    #pragma unroll
    for (int m = 1; m < 16; m <<= 1) {
        #pragma unroll
        for (int reg = 0; reg < 4; ++reg)
            part[reg] += __shfl_xor(part[reg], m);
    }
    if (l15 < 4) {
        int row = w * 16 + quad * 4 + l15;
        if (p0 + row < E) {
            int eo = pe[row];
            out[eo] = 1.0f / (1.0f + expf(-(part[l15] + b3[0])));
        }
    }
}

// ---------------------------------------------------------------------------
extern "C" void kernel_launch(void* const* d_in, const int* in_sizes, int n_in,
                              void* d_out, int out_size, void* d_ws, size_t ws_size,
                              hipStream_t stream) {
    const float* x_u     = (const float*)d_in[0];
    const float* x_r     = (const float*)d_in[1];
    const float* eattr   = (const float*)d_in[2];
    const int*   ei_ut   = (const int*)d_in[3];
    const int*   ei_ru   = (const int*)d_in[4];
    const float* proj_uW = (const float*)d_in[5];
    const float* proj_ub = (const float*)d_in[6];
    const float* proj_rW = (const float*)d_in[7];
    const float* proj_rb = (const float*)d_in[8];
    const float* sage_Wl = (const float*)d_in[9];
    const float* sage_bl = (const float*)d_in[10];
    const float* sage_Wr = (const float*)d_in[11];
    const float* bn_g    = (const float*)d_in[12];
    const float* bn_b    = (const float*)d_in[13];
    const float* bn_m    = (const float*)d_in[14];
    const float* bn_v    = (const float*)d_in[15];
    const float* ep_W1   = (const float*)d_in[16];
    const float* ep_b1   = (const float*)d_in[17];
    const float* ep_bng  = (const float*)d_in[18];
    const float* ep_bnb  = (const float*)d_in[19];
    const float* ep_bnm  = (const float*)d_in[20];
    const float* ep_bnv  = (const float*)d_in[21];
    const float* ep_W2   = (const float*)d_in[22];
    const float* ep_b2   = (const float*)d_in[23];
    const float* ep_W3   = (const float*)d_in[24];
    const float* ep_b3   = (const float*)d_in[25];

    int Nu = in_sizes[0] / 32;
    int Nr = in_sizes[1] / 32;
    int E  = in_sizes[3] / 2;

    // ---- workspace ----
    unsigned short* us = (unsigned short*)d_ws;
    unsigned short* h0_u = us;   us += (size_t)Nu * H;
    unsigned short* h0_r = us;   us += (size_t)Nr * H;
    unsigned short* h1_u = us;   us += (size_t)Nu * H;
    unsigned short* h1_r = us;   us += (size_t)Nr * H;
    unsigned short* W1f  = us;   us += 36864;
    unsigned short* W2f  = us;   us += 8192;
    unsigned short* puf  = us;   us += 4096;
    unsigned short* prf  = us;   us += 4096;
    unsigned short* sageWf = us; us += 131072;
    int* ip     = (int*)us;
    int* off_r  = ip;  ip += Nr + 1;
    int* off_u  = ip;  ip += Nu + 1;
    int* deg_r  = ip;  ip += Nr;      // deg_r/deg_u contiguous (one memset)
    int* deg_u  = ip;  ip += Nu;
    int* eid_r  = ip;  ip += E;
    int* eid_u  = ip;  ip += E;
    int* eperm_r = ip; ip += E;
    int* epdst_r = ip; ip += E;
    int* part_r = ip;  ip += 512;
    int* part_u = ip;  ip += 512;

    const int* ut_src = ei_ut;
    const int* ut_dst = ei_ut + E;
    const int* ru_src = ei_ru;
    const int* ru_dst = ei_ru + E;

    int EB  = (E + 255) / 256;
    int NBr = (Nr + 255) / 256;
    int NBu = (Nu + 255) / 256;

    // ---- weight fragments ----
    wfrag_all<<<90, 256, 0, stream>>>(ep_W1, ep_W2, proj_uW, proj_rW,
                                      sage_Wl, sage_Wr,
                                      W1f, W2f, puf, prf, sageWf);

    // ---- CSR build (scan2 folded into scan3) ----
    hipMemsetAsync(deg_r, 0, (size_t)(Nr + Nu) * sizeof(int), stream);
    hist_kernel<<<2 * EB, 256, 0, stream>>>(ut_dst, ru_dst, deg_r, deg_u, E, EB);
    scan1_kernel<<<NBr + NBu, 256, 0, stream>>>(deg_r, deg_u, part_r, part_u, Nr, Nu, NBr);
    scan3_kernel<<<NBr + NBu, 256, 0, stream>>>(deg_r, deg_u, part_r, part_u,
                                                off_r, off_u, Nr, Nu, NBr);
    fill_kernel<<<2 * EB, 256, 0, stream>>>(ut_src, ut_dst, ru_src, ru_dst,
                                            off_r, off_u, deg_r, deg_u,
                                            eid_r, eid_u, eperm_r, epdst_r, E, EB);

    // ---- input projections ----
    int nbu = (Nu + 63) / 64, nbr = (Nr + 63) / 64;
    proj_kernel<<<nbu + nbr, 256, 0, stream>>>(x_u, x_r, puf, proj_ub, prf, proj_rb,
                                               h0_u, h0_r, Nu, Nr, nbu);

    // ---- 2 fused layers (ping-pong h0 -> h1 -> h0) ----
    for (int layer = 0; layer < 2; ++layer) {
        const unsigned short* iu = (layer == 0) ? h0_u : h1_u;
        const unsigned short* ir = (layer == 0) ? h0_r : h1_r;
        unsigned short* ou = (layer == 0) ? h1_u : h0_u;
        unsigned short* orr = (layer == 0) ? h1_r : h0_r;

        const unsigned short* Wf0 = sageWf + ((size_t)layer * 2 + 0) * 32768;
        const unsigned short* Wf1 = sageWf + ((size_t)layer * 2 + 1) * 32768;
        const float* bl0 = sage_bl + ((size_t)layer * 2 + 0) * H;
        const float* bl1 = sage_bl + ((size_t)layer * 2 + 1) * H;
        const float* g0 = bn_g + ((size_t)layer * 2 + 0) * H;   // user BN
        const float* b0 = bn_b + ((size_t)layer * 2 + 0) * H;
        const float* m0 = bn_m + ((size_t)layer * 2 + 0) * H;
        const float* v0 = bn_v + ((size_t)layer * 2 + 0) * H;
        const float* g1 = bn_g + ((size_t)layer * 2 + 1) * H;   // recipient BN
        const float* b1 = bn_b + ((size_t)layer * 2 + 1) * H;
        const float* m1 = bn_m + ((size_t)layer * 2 + 1) * H;
        const float* v1 = bn_v + ((size_t)layer * 2 + 1) * H;

        layer_kernel<<<nbr + nbu, 256, 0, stream>>>(
            iu, ir, ou, orr,
            off_r, eid_r, off_u, eid_u,
            Nu, Nr, nbr,
            Wf0, bl0, g1, b1, m1, v1,    // recipient side (edge type 0, BN type 1)
            Wf1, bl1, g0, b0, m0, v0);   // user side (edge type 1, BN type 0)
    }

    ep_kernel<<<(E + 63) / 64, 256, 0, stream>>>(h0_u, h0_r, eattr,
                                                 eid_r, epdst_r, eperm_r,
                                                 W1f, ep_b1,
                                                 ep_bng, ep_bnb, ep_bnm, ep_bnv,
                                                 W2f, ep_b2, ep_W3, ep_b3,
                                                 (float*)d_out, E);
}

// Round 10
// 550.407 us; speedup vs baseline: 2.9091x; 1.0062x over previous
//
#include <hip/hip_runtime.h>
#include <math.h>

#define H 128
#define BN_EPS 1e-5f

typedef __attribute__((ext_vector_type(8))) short bf16x8;
typedef __attribute__((ext_vector_type(4))) float f32x4;
typedef __attribute__((ext_vector_type(2))) float f32x2;

__device__ __forceinline__ unsigned short f2bf(float f) {
    unsigned int u = __float_as_uint(f);
    u += 0x7fffu + ((u >> 16) & 1u);
    return (unsigned short)(u >> 16);
}
__device__ __forceinline__ float bf2f(unsigned short s) {
    return __uint_as_float(((unsigned int)s) << 16);
}
__device__ __forceinline__ f32x4 mfma16(bf16x8 a, bf16x8 b, f32x4 c) {
    return __builtin_amdgcn_mfma_f32_16x16x32_bf16(a, b, c, 0, 0, 0);
}
// fp8 e4m3 (OCP on gfx950) encode/decode via HW cvt
__device__ __forceinline__ unsigned char f2fp8(float f) {
    int p = __builtin_amdgcn_cvt_pk_fp8_f32(f, f, 0, false);
    return (unsigned char)(p & 0xff);
}

// ---------------------------------------------------------------------------
// Weight fragment pre-transpose into MFMA B-operand layout (bf16)
// ---------------------------------------------------------------------------
__device__ __forceinline__ void wfrag_one(const float* __restrict__ src,
                                          unsigned short* __restrict__ dst,
                                          int K, int N, int idx) {
    int l = idx & 63;
    int rest = idx >> 6;
    int ntn = N >> 4;
    int nt = rest % ntn;
    int kc = rest / ntn;
    int n = nt * 16 + (l & 15);
    int k0 = kc * 32 + (l >> 4) * 8;
    bf16x8 v;
    #pragma unroll
    for (int j = 0; j < 8; ++j) {
        int k = k0 + j;
        v[j] = (short)((k < K) ? f2bf(src[(size_t)k * N + n]) : 0);
    }
    *(bf16x8*)(dst + (size_t)idx * 8) = v;
}

__global__ __launch_bounds__(256)
void wfrag_all(const float* __restrict__ W1, const float* __restrict__ W2,
               const float* __restrict__ pu, const float* __restrict__ pr,
               const float* __restrict__ Wl, const float* __restrict__ Wr,
               unsigned short* __restrict__ W1f, unsigned short* __restrict__ W2f,
               unsigned short* __restrict__ puf, unsigned short* __restrict__ prf,
               unsigned short* __restrict__ sageWf) {
    int bx = blockIdx.x;
    if (bx < 26) {
        int idx = bx * 256 + threadIdx.x;
        if (idx < 4608)      wfrag_one(W1, W1f, 272, 128, idx);          // K=272 pad 288
        else if (idx < 5632) wfrag_one(W2, W2f, 128, 64, idx - 4608);
        else if (idx < 6144) wfrag_one(pu, puf, 32, 128, idx - 5632);
        else if (idx < 6656) wfrag_one(pr, prf, 32, 128, idx - 6144);
    } else {
        int idx = (bx - 26) * 256 + threadIdx.x;   // < 16384
        int seg = idx >> 11;
        int sub = idx & 2047;
        int lt = seg >> 1;                          // layer*2+type
        int half = seg & 1;                         // 0=Wl, 1=Wr
        const float* src = (half ? Wr : Wl) + (size_t)lt * H * H;
        unsigned short* dst = sageWf + (size_t)lt * 32768 + half * 16384;
        wfrag_one(src, dst, 128, 128, sub);
    }
}

// swizzled fp8 shadow byte index for logical column col:
//   col = kc*32 + q*8 + j  ->  swz = q*32 + kc*8 + j
__device__ __forceinline__ int swz_of(int col) {
    int kc = col >> 5;
    int q = (col >> 3) & 3;
    int j = col & 7;
    return q * 32 + kc * 8 + j;
}

// ---------------------------------------------------------------------------
// Input projection via MFMA: h = x @ W + b -> bf16 h + fp8 swizzled shadow
// ---------------------------------------------------------------------------
__global__ __launch_bounds__(256)
void proj_kernel(const float* __restrict__ xu, const float* __restrict__ xr,
                 const unsigned short* __restrict__ puf, const float* __restrict__ bu,
                 const unsigned short* __restrict__ prf, const float* __restrict__ br,
                 unsigned short* __restrict__ hub, unsigned short* __restrict__ hrb,
                 unsigned char* __restrict__ h8u, unsigned char* __restrict__ h8r,
                 int Nu, int Nr, int nbu) {
    int bx = blockIdx.x;
    const float* x; const unsigned short* Wf; const float* bias;
    unsigned short* hb; unsigned char* h8; int N; int row0;
    if (bx < nbu) { x = xu; Wf = puf; bias = bu; hb = hub; h8 = h8u; N = Nu; row0 = bx * 64; }
    else          { x = xr; Wf = prf; bias = br; hb = hrb; h8 = h8r; N = Nr; row0 = (bx - nbu) * 64; }

    int tid = threadIdx.x, l = tid & 63, w = tid >> 6, l15 = l & 15, quad = l >> 4;
    int arow = row0 + w * 16 + l15;

    bf16x8 a = {0, 0, 0, 0, 0, 0, 0, 0};
    if (arow < N) {
        const float* xp = x + (size_t)arow * 32 + quad * 8;
        float4 v0 = *(const float4*)xp;
        float4 v1 = *(const float4*)(xp + 4);
        a[0] = (short)f2bf(v0.x); a[1] = (short)f2bf(v0.y);
        a[2] = (short)f2bf(v0.z); a[3] = (short)f2bf(v0.w);
        a[4] = (short)f2bf(v1.x); a[5] = (short)f2bf(v1.y);
        a[6] = (short)f2bf(v1.z); a[7] = (short)f2bf(v1.w);
    }
    f32x4 acc[8];
    #pragma unroll
    for (int nt = 0; nt < 8; ++nt) {
        bf16x8 b = *(const bf16x8*)(Wf + (size_t)(nt * 64 + l) * 8);
        acc[nt] = mfma16(a, b, (f32x4){0.f, 0.f, 0.f, 0.f});
    }
    #pragma unroll
    for (int reg = 0; reg < 4; ++reg) {
        int row = row0 + w * 16 + quad * 4 + reg;
        if (row < N) {
            #pragma unroll
            for (int nt = 0; nt < 8; ++nt) {
                int col = nt * 16 + l15;
                float v = acc[nt][reg] + bias[col];
                hb[(size_t)row * H + col] = f2bf(v);
                h8[(size_t)row * H + swz_of(col)] = f2fp8(v);
            }
        }
    }
}

// ---------------------------------------------------------------------------
// CSR build (both edge types per dispatch)
// ---------------------------------------------------------------------------
__global__ __launch_bounds__(256)
void hist_kernel(const int* __restrict__ dstR, const int* __restrict__ dstU,
                 int* __restrict__ degR, int* __restrict__ degU, int E, int EB) {
    int bx = blockIdx.x;
    const int* dst = (bx < EB) ? dstR : dstU;
    int* deg = (bx < EB) ? degR : degU;
    int e = ((bx < EB) ? bx : bx - EB) * 256 + threadIdx.x;
    if (e < E) atomicAdd(&deg[dst[e]], 1);
}

__global__ __launch_bounds__(256)
void scan1_kernel(const int* __restrict__ degR, const int* __restrict__ degU,
                  int* __restrict__ partR, int* __restrict__ partU, int Nr, int Nu, int NBr) {
    int bx = blockIdx.x;
    const int* deg = (bx < NBr) ? degR : degU;
    int* part = (bx < NBr) ? partR : partU;
    int lb = (bx < NBr) ? bx : bx - NBr;
    int N = (bx < NBr) ? Nr : Nu;
    __shared__ int s[256];
    int t = threadIdx.x;
    int i = lb * 256 + t;
    s[t] = (i < N) ? deg[i] : 0;
    __syncthreads();
    for (int o = 128; o > 0; o >>= 1) {
        if (t < o) s[t] += s[t + o];
        __syncthreads();
    }
    if (t == 0) part[lb] = s[0];
}

// scan3 computes the global prefix of raw block sums itself (no scan2)
__global__ __launch_bounds__(256)
void scan3_kernel(const int* __restrict__ degR, const int* __restrict__ degU,
                  const int* __restrict__ partR, const int* __restrict__ partU,
                  int* __restrict__ offR, int* __restrict__ offU, int Nr, int Nu, int NBr) {
    int bx = blockIdx.x;
    const int* deg = (bx < NBr) ? degR : degU;
    const int* part = (bx < NBr) ? partR : partU;
    int* off = (bx < NBr) ? offR : offU;
    int lb = (bx < NBr) ? bx : bx - NBr;
    int N = (bx < NBr) ? Nr : Nu;
    __shared__ int s[256];
    __shared__ int ps[256];
    int t = threadIdx.x;

    int pv = 0;
    if (t < lb) pv += part[t];
    if (t + 256 < lb) pv += part[t + 256];
    ps[t] = pv;
    __syncthreads();
    for (int o = 128; o > 0; o >>= 1) {
        if (t < o) ps[t] += ps[t + o];
        __syncthreads();
    }
    int pref = ps[0];

    int i = lb * 256 + t;
    int v = (i < N) ? deg[i] : 0;
    s[t] = v;
    __syncthreads();
    for (int o = 1; o < 256; o <<= 1) {
        int x = (t >= o) ? s[t - o] : 0;
        __syncthreads();
        s[t] += x;
        __syncthreads();
    }
    if (i < N) off[i] = pref + s[t] - v;
    if (i == N - 1) off[N] = pref + s[t];
}

__global__ __launch_bounds__(256)
void fill_kernel(const int* __restrict__ srcR, const int* __restrict__ dstR,
                 const int* __restrict__ srcU, const int* __restrict__ dstU,
                 const int* __restrict__ offR, const int* __restrict__ offU,
                 int* __restrict__ degR, int* __restrict__ degU,
                 int* __restrict__ eidR, int* __restrict__ eidU,
                 int* __restrict__ epermR, int* __restrict__ epdstR,
                 int E, int EB) {
    int bx = blockIdx.x;
    bool isR = bx < EB;
    const int* src = isR ? srcR : srcU;
    const int* dst = isR ? dstR : dstU;
    const int* off = isR ? offR : offU;
    int* deg = isR ? degR : degU;
    int* eid = isR ? eidR : eidU;
    int e = (isR ? bx : bx - EB) * 256 + threadIdx.x;
    if (e < E) {
        int d = dst[e];
        int p = off[d] + atomicSub(&deg[d], 1) - 1;
        eid[p] = src[e];
        if (isR) {
            epermR[p] = e;
            epdstR[p] = d;
        }
    }
}

// ---------------------------------------------------------------------------
// Fused layer: gather-mean (fp8 swizzled rows) + SAGE + BN + ReLU + residual.
// In-block degree sort (wave-0 bitonic) for uniform CSR walks.
// ---------------------------------------------------------------------------
__global__ __launch_bounds__(256)
void layer_kernel(const unsigned short* __restrict__ hu_o, const unsigned short* __restrict__ hr_o,
                  const unsigned char* __restrict__ h8u_o, const unsigned char* __restrict__ h8r_o,
                  unsigned short* __restrict__ hu_n, unsigned short* __restrict__ hr_n,
                  unsigned char* __restrict__ h8u_n, unsigned char* __restrict__ h8r_n,
                  const int* __restrict__ off_r, const int* __restrict__ eid_r,
                  const int* __restrict__ off_u, const int* __restrict__ eid_u,
                  int Nu, int Nr, int nbr,
                  const unsigned short* __restrict__ WfR, const float* __restrict__ blR,
                  const float* __restrict__ gR, const float* __restrict__ bR,
                  const float* __restrict__ mR, const float* __restrict__ vR,
                  const unsigned short* __restrict__ WfU, const float* __restrict__ blU,
                  const float* __restrict__ gU, const float* __restrict__ bU,
                  const float* __restrict__ mU, const float* __restrict__ vU) {
    int bx = blockIdx.x;
    const unsigned short* own; const unsigned char* g8; unsigned short* outp; unsigned char* out8;
    const int* off; const int* eid; const unsigned short* Wf;
    const float *bl, *bg, *bb, *bm, *bv;
    int N, row0;
    if (bx < nbr) {
        g8 = h8u_o; own = hr_o; outp = hr_n; out8 = h8r_n; off = off_r; eid = eid_r;
        Wf = WfR; bl = blR; bg = gR; bb = bR; bm = mR; bv = vR;
        N = Nr; row0 = bx * 64;
    } else {
        g8 = h8r_o; own = hu_o; outp = hu_n; out8 = h8u_n; off = off_u; eid = eid_u;
        Wf = WfU; bl = blU; bg = gU; bb = bU; bm = mU; bv = vU;
        N = Nu; row0 = (bx - nbr) * 64;
    }

    __shared__ float sc[128], sh[128], bias[128];
    __shared__ int perm[64];
    int tid = threadIdx.x;
    if (tid < 128) {
        float s = bg[tid] * rsqrtf(bv[tid] + BN_EPS);
        sc[tid] = s;
        sh[tid] = bb[tid] - bm[tid] * s;
        bias[tid] = bl[tid];
    }
    if (tid < 64) {
        int rr = row0 + tid;
        int dg = (rr < N) ? (off[rr + 1] - off[rr]) : 0;
        int key = (min(dg, 255) << 8) | tid;
        for (int k = 2; k <= 64; k <<= 1) {
            for (int j = k >> 1; j > 0; j >>= 1) {
                int p = __shfl_xor(key, j);
                bool keepmin = (((tid & j) == 0) == ((tid & k) == 0));
                key = keepmin ? (key < p ? key : p) : (key > p ? key : p);
            }
        }
        perm[tid] = key & 255;
    }
    __syncthreads();

    int l = tid & 63, w = tid >> 6, l15 = l & 15, quad = l >> 4;
    int rloc = perm[w * 16 + l15];
    int arow = row0 + rloc;
    bool rok = (arow < N);
    size_t rbase = (size_t)(rok ? arow : 0) * H;
    int s0 = rok ? off[arow] : 0;
    int s1 = rok ? off[arow + 1] : 0;

    // preload own-row bf16 fragments (in flight across the gather loop)
    bf16x8 ownfr[4];
    #pragma unroll
    for (int kc = 0; kc < 4; ++kc)
        ownfr[kc] = *(const bf16x8*)(own + rbase + kc * 32 + quad * 8);

    // gather-mean from fp8 swizzled rows: 2x16B loads per edge per lane
    float ag[4][8];
    #pragma unroll
    for (int kc = 0; kc < 4; ++kc)
        #pragma unroll
        for (int j = 0; j < 8; ++j) ag[kc][j] = 0.0f;

    for (int i = s0; i < s1; ++i) {
        int s = eid[i];
        const uint4* rp = (const uint4*)(g8 + (size_t)s * H + quad * 32);
        uint4 w0 = rp[0];   // kc0 (x,y), kc1 (z,w)
        uint4 w1 = rp[1];   // kc2 (x,y), kc3 (z,w)
        #define ACC4(word, kc, jb) { \
            f32x2 lo_ = __builtin_amdgcn_cvt_pk_f32_fp8((int)(word), false); \
            f32x2 hi_ = __builtin_amdgcn_cvt_pk_f32_fp8((int)(word), true);  \
            ag[kc][jb + 0] += lo_[0]; ag[kc][jb + 1] += lo_[1]; \
            ag[kc][jb + 2] += hi_[0]; ag[kc][jb + 3] += hi_[1]; }
        ACC4(w0.x, 0, 0) ACC4(w0.y, 0, 4) ACC4(w0.z, 1, 0) ACC4(w0.w, 1, 4)
        ACC4(w1.x, 2, 0) ACC4(w1.y, 2, 4) ACC4(w1.z, 3, 0) ACC4(w1.w, 3, 4)
        #undef ACC4
    }
    float inv = (s1 > s0) ? 1.0f / (float)(s1 - s0) : 0.0f;

    f32x4 acc[8];
    #pragma unroll
    for (int nt = 0; nt < 8; ++nt) acc[nt] = (f32x4){0.f, 0.f, 0.f, 0.f};

    #pragma unroll
    for (int kc = 0; kc < 4; ++kc) {
        bf16x8 a;
        #pragma unroll
        for (int j = 0; j < 8; ++j) a[j] = (short)f2bf(ag[kc][j] * inv);
        #pragma unroll
        for (int nt = 0; nt < 8; ++nt) {
            bf16x8 b = *(const bf16x8*)(Wf + (size_t)((kc * 8 + nt) * 64 + l) * 8);
            acc[nt] = mfma16(a, b, acc[nt]);
        }
    }
    #pragma unroll
    for (int kc = 4; kc < 8; ++kc) {
        #pragma unroll
        for (int nt = 0; nt < 8; ++nt) {
            bf16x8 b = *(const bf16x8*)(Wf + (size_t)((kc * 8 + nt) * 64 + l) * 8);
            acc[nt] = mfma16(ownfr[kc - 4], b, acc[nt]);
        }
    }

    // epilogue: bias -> BN -> ReLU -> + residual; bf16 + fp8 shadow stores
    #pragma unroll
    for (int reg = 0; reg < 4; ++reg) {
        int crow = row0 + perm[w * 16 + quad * 4 + reg];
        if (crow < N) {
            #pragma unroll
            for (int nt = 0; nt < 8; ++nt) {
                int col = nt * 16 + l15;
                float g = acc[nt][reg] + bias[col];
                g = g * sc[col] + sh[col];
                float hv = bf2f(own[(size_t)crow * H + col]);
                float o = fmaxf(g, 0.0f) + hv;
                outp[(size_t)crow * H + col] = f2bf(o);
                out8[(size_t)crow * H + swz_of(col)] = f2fp8(o);
            }
        }
    }
}

// ---------------------------------------------------------------------------
// Edge predictor via MFMA, CSR slot order; src/dst rows gathered as fp8
// swizzled (2x16B each), converted to bf16 frags; W stays bf16.
// ---------------------------------------------------------------------------
__device__ __forceinline__ bf16x8 frag_fp8pair(unsigned int wa, unsigned int wb) {
    f32x2 a0 = __builtin_amdgcn_cvt_pk_f32_fp8((int)wa, false);
    f32x2 a1 = __builtin_amdgcn_cvt_pk_f32_fp8((int)wa, true);
    f32x2 b0 = __builtin_amdgcn_cvt_pk_f32_fp8((int)wb, false);
    f32x2 b1 = __builtin_amdgcn_cvt_pk_f32_fp8((int)wb, true);
    bf16x8 r;
    r[0] = (short)f2bf(a0[0]); r[1] = (short)f2bf(a0[1]);
    r[2] = (short)f2bf(a1[0]); r[3] = (short)f2bf(a1[1]);
    r[4] = (short)f2bf(b0[0]); r[5] = (short)f2bf(b0[1]);
    r[6] = (short)f2bf(b1[0]); r[7] = (short)f2bf(b1[1]);
    return r;
}

__global__ __launch_bounds__(256)
void ep_kernel(const unsigned char* __restrict__ h8u, const unsigned char* __restrict__ h8r,
               const float* __restrict__ ea,
               const int* __restrict__ slot_src, const int* __restrict__ slot_dst,
               const int* __restrict__ slot_eid,
               const unsigned short* __restrict__ W1f, const float* __restrict__ b1,
               const float* __restrict__ bng, const float* __restrict__ bnb,
               const float* __restrict__ bnm, const float* __restrict__ bnv,
               const unsigned short* __restrict__ W2f, const float* __restrict__ b2,
               const float* __restrict__ W3, const float* __restrict__ b3,
               float* __restrict__ out, int E) {
    __shared__ unsigned short h1s[64][136];
    __shared__ int se[64], de[64], pe[64];
    __shared__ float sc1[128], sh1[128], bi1[128];

    int tid = threadIdx.x;
    int p0 = blockIdx.x * 64;
    if (tid < 64) {
        int p = p0 + tid;
        bool v = (p < E);
        se[tid] = v ? slot_src[p] : 0;
        de[tid] = v ? slot_dst[p] : 0;
        pe[tid] = v ? slot_eid[p] : 0;
    }
    if (tid < 128) {
        float s = bng[tid] * rsqrtf(bnv[tid] + BN_EPS);
        sc1[tid] = s;
        sh1[tid] = bnb[tid] - bnm[tid] * s;
        bi1[tid] = b1[tid];
    }
    __syncthreads();

    int l = tid & 63, w = tid >> 6, l15 = l & 15, quad = l >> 4;
    int arow = w * 16 + l15;
    int eorig = pe[arow];
    bool ev = (p0 + arow < E);

    // ---- preload: 2x16B src + 2x16B dst + eattr, all in flight ----
    const uint4* sp = (const uint4*)(h8u + (size_t)se[arow] * H + quad * 32);
    const uint4* dp = (const uint4*)(h8r + (size_t)de[arow] * H + quad * 32);
    uint4 sw0 = sp[0], sw1 = sp[1];
    uint4 dw0 = dp[0], dw1 = dp[1];
    bf16x8 aea = {0, 0, 0, 0, 0, 0, 0, 0};
    if (quad < 2 && ev) {
        const float* p = ea + (size_t)eorig * 16 + quad * 8;
        float4 v0 = *(const float4*)p;
        float4 v1 = *(const float4*)(p + 4);
        aea[0] = (short)f2bf(v0.x); aea[1] = (short)f2bf(v0.y);
        aea[2] = (short)f2bf(v0.z); aea[3] = (short)f2bf(v0.w);
        aea[4] = (short)f2bf(v1.x); aea[5] = (short)f2bf(v1.y);
        aea[6] = (short)f2bf(v1.z); aea[7] = (short)f2bf(v1.w);
    }
    bf16x8 afr[9];
    afr[0] = frag_fp8pair(sw0.x, sw0.y);
    afr[1] = frag_fp8pair(sw0.z, sw0.w);
    afr[2] = frag_fp8pair(sw1.x, sw1.y);
    afr[3] = frag_fp8pair(sw1.z, sw1.w);
    afr[4] = frag_fp8pair(dw0.x, dw0.y);
    afr[5] = frag_fp8pair(dw0.z, dw0.w);
    afr[6] = frag_fp8pair(dw1.x, dw1.y);
    afr[7] = frag_fp8pair(dw1.z, dw1.w);
    afr[8] = aea;

    f32x4 acc[8];
    #pragma unroll
    for (int nt = 0; nt < 8; ++nt) acc[nt] = (f32x4){0.f, 0.f, 0.f, 0.f};

    #pragma unroll
    for (int kc = 0; kc < 9; ++kc) {
        #pragma unroll
        for (int nt = 0; nt < 8; ++nt) {
            bf16x8 b = *(const bf16x8*)(W1f + (size_t)((kc * 8 + nt) * 64 + l) * 8);
            acc[nt] = mfma16(afr[kc], b, acc[nt]);
        }
    }

    // phase-1 epilogue: bias -> relu -> bn -> bf16 h1s
    #pragma unroll
    for (int nt = 0; nt < 8; ++nt) {
        #pragma unroll
        for (int reg = 0; reg < 4; ++reg) {
            int row = w * 16 + quad * 4 + reg;
            int col = nt * 16 + l15;
            float z = acc[nt][reg] + bi1[col];
            z = fmaxf(z, 0.0f);
            z = z * sc1[col] + sh1[col];
            h1s[row][col] = f2bf(z);
        }
    }
    __syncthreads();

    // phase 2: h2 = relu(h1 @ W2 + b2), K=128, N=64
    f32x4 acc2[4];
    #pragma unroll
    for (int nt = 0; nt < 4; ++nt) acc2[nt] = (f32x4){0.f, 0.f, 0.f, 0.f};
    #pragma unroll
    for (int kc = 0; kc < 4; ++kc) {
        bf16x8 a2 = *(const bf16x8*)&h1s[w * 16 + l15][kc * 32 + quad * 8];
        #pragma unroll
        for (int nt = 0; nt < 4; ++nt) {
            bf16x8 b = *(const bf16x8*)(W2f + (size_t)((kc * 4 + nt) * 64 + l) * 8);
            acc2[nt] = mfma16(a2, b, acc2[nt]);
        }
    }

    // phase 3: per-row dot with W3 via quad shuffle reduction
    float part[4] = {0.f, 0.f, 0.f, 0.f};
    #pragma unroll
    for (int nt = 0; nt < 4; ++nt) {
        int col = nt * 16 + l15;
        float w3v = W3[col];
        float b2v = b2[col];
        #pragma unroll
        for (int reg = 0; reg < 4; ++reg)
            part[reg] += fmaxf(acc2[nt][reg] + b2v, 0.0f) * w3v;
    }
    #pragma unroll
    for (int m = 1; m < 16; m <<= 1) {
        #pragma unroll
        for (int reg = 0; reg < 4; ++reg)
            part[reg] += __shfl_xor(part[reg], m);
    }
    if (l15 < 4) {
        int row = w * 16 + quad * 4 + l15;
        if (p0 + row < E) {
            int eo = pe[row];
            out[eo] = 1.0f / (1.0f + expf(-(part[l15] + b3[0])));
        }
    }
}

// ---------------------------------------------------------------------------
extern "C" void kernel_launch(void* const* d_in, const int* in_sizes, int n_in,
                              void* d_out, int out_size, void* d_ws, size_t ws_size,
                              hipStream_t stream) {
    const float* x_u     = (const float*)d_in[0];
    const float* x_r     = (const float*)d_in[1];
    const float* eattr   = (const float*)d_in[2];
    const int*   ei_ut   = (const int*)d_in[3];
    const int*   ei_ru   = (const int*)d_in[4];
    const float* proj_uW = (const float*)d_in[5];
    const float* proj_ub = (const float*)d_in[6];
    const float* proj_rW = (const float*)d_in[7];
    const float* proj_rb = (const float*)d_in[8];
    const float* sage_Wl = (const float*)d_in[9];
    const float* sage_bl = (const float*)d_in[10];
    const float* sage_Wr = (const float*)d_in[11];
    const float* bn_g    = (const float*)d_in[12];
    const float* bn_b    = (const float*)d_in[13];
    const float* bn_m    = (const float*)d_in[14];
    const float* bn_v    = (const float*)d_in[15];
    const float* ep_W1   = (const float*)d_in[16];
    const float* ep_b1   = (const float*)d_in[17];
    const float* ep_bng  = (const float*)d_in[18];
    const float* ep_bnb  = (const float*)d_in[19];
    const float* ep_bnm  = (const float*)d_in[20];
    const float* ep_bnv  = (const float*)d_in[21];
    const float* ep_W2   = (const float*)d_in[22];
    const float* ep_b2   = (const float*)d_in[23];
    const float* ep_W3   = (const float*)d_in[24];
    const float* ep_b3   = (const float*)d_in[25];

    int Nu = in_sizes[0] / 32;
    int Nr = in_sizes[1] / 32;
    int E  = in_sizes[3] / 2;

    // ---- workspace ----
    unsigned short* us = (unsigned short*)d_ws;
    unsigned short* h0_u = us;   us += (size_t)Nu * H;
    unsigned short* h0_r = us;   us += (size_t)Nr * H;
    unsigned short* h1_u = us;   us += (size_t)Nu * H;
    unsigned short* h1_r = us;   us += (size_t)Nr * H;
    unsigned short* W1f  = us;   us += 36864;
    unsigned short* W2f  = us;   us += 8192;
    unsigned short* puf  = us;   us += 4096;
    unsigned short* prf  = us;   us += 4096;
    unsigned short* sageWf = us; us += 131072;
    unsigned char* f80_u = (unsigned char*)us;
    unsigned char* f80_r = f80_u + (size_t)Nu * H;
    unsigned char* f81_u = f80_r + (size_t)Nr * H;
    unsigned char* f81_r = f81_u + (size_t)Nu * H;
    int* ip     = (int*)(f81_r + (size_t)Nr * H);
    int* off_r  = ip;  ip += Nr + 1;
    int* off_u  = ip;  ip += Nu + 1;
    int* deg_r  = ip;  ip += Nr;      // deg_r/deg_u contiguous (one memset)
    int* deg_u  = ip;  ip += Nu;
    int* eid_r  = ip;  ip += E;
    int* eid_u  = ip;  ip += E;
    int* eperm_r = ip; ip += E;
    int* epdst_r = ip; ip += E;
    int* part_r = ip;  ip += 512;
    int* part_u = ip;  ip += 512;

    const int* ut_src = ei_ut;
    const int* ut_dst = ei_ut + E;
    const int* ru_src = ei_ru;
    const int* ru_dst = ei_ru + E;

    int EB  = (E + 255) / 256;
    int NBr = (Nr + 255) / 256;
    int NBu = (Nu + 255) / 256;

    // ---- weight fragments ----
    wfrag_all<<<90, 256, 0, stream>>>(ep_W1, ep_W2, proj_uW, proj_rW,
                                      sage_Wl, sage_Wr,
                                      W1f, W2f, puf, prf, sageWf);

    // ---- CSR build ----
    hipMemsetAsync(deg_r, 0, (size_t)(Nr + Nu) * sizeof(int), stream);
    hist_kernel<<<2 * EB, 256, 0, stream>>>(ut_dst, ru_dst, deg_r, deg_u, E, EB);
    scan1_kernel<<<NBr + NBu, 256, 0, stream>>>(deg_r, deg_u, part_r, part_u, Nr, Nu, NBr);
    scan3_kernel<<<NBr + NBu, 256, 0, stream>>>(deg_r, deg_u, part_r, part_u,
                                                off_r, off_u, Nr, Nu, NBr);
    fill_kernel<<<2 * EB, 256, 0, stream>>>(ut_src, ut_dst, ru_src, ru_dst,
                                            off_r, off_u, deg_r, deg_u,
                                            eid_r, eid_u, eperm_r, epdst_r, E, EB);

    // ---- input projections ----
    int nbu = (Nu + 63) / 64, nbr = (Nr + 63) / 64;
    proj_kernel<<<nbu + nbr, 256, 0, stream>>>(x_u, x_r, puf, proj_ub, prf, proj_rb,
                                               h0_u, h0_r, f80_u, f80_r, Nu, Nr, nbu);

    // ---- 2 fused layers (ping-pong h0 -> h1 -> h0, fp8 shadows alongside) ----
    for (int layer = 0; layer < 2; ++layer) {
        const unsigned short* iu = (layer == 0) ? h0_u : h1_u;
        const unsigned short* ir = (layer == 0) ? h0_r : h1_r;
        const unsigned char* i8u = (layer == 0) ? f80_u : f81_u;
        const unsigned char* i8r = (layer == 0) ? f80_r : f81_r;
        unsigned short* ou = (layer == 0) ? h1_u : h0_u;
        unsigned short* orr = (layer == 0) ? h1_r : h0_r;
        unsigned char* o8u = (layer == 0) ? f81_u : f80_u;
        unsigned char* o8r = (layer == 0) ? f81_r : f80_r;

        const unsigned short* Wf0 = sageWf + ((size_t)layer * 2 + 0) * 32768;
        const unsigned short* Wf1 = sageWf + ((size_t)layer * 2 + 1) * 32768;
        const float* bl0 = sage_bl + ((size_t)layer * 2 + 0) * H;
        const float* bl1 = sage_bl + ((size_t)layer * 2 + 1) * H;
        const float* g0 = bn_g + ((size_t)layer * 2 + 0) * H;   // user BN
        const float* b0 = bn_b + ((size_t)layer * 2 + 0) * H;
        const float* m0 = bn_m + ((size_t)layer * 2 + 0) * H;
        const float* v0 = bn_v + ((size_t)layer * 2 + 0) * H;
        const float* g1 = bn_g + ((size_t)layer * 2 + 1) * H;   // recipient BN
        const float* b1 = bn_b + ((size_t)layer * 2 + 1) * H;
        const float* m1 = bn_m + ((size_t)layer * 2 + 1) * H;
        const float* v1 = bn_v + ((size_t)layer * 2 + 1) * H;

        layer_kernel<<<nbr + nbu, 256, 0, stream>>>(
            iu, ir, i8u, i8r, ou, orr, o8u, o8r,
            off_r, eid_r, off_u, eid_u,
            Nu, Nr, nbr,
            Wf0, bl0, g1, b1, m1, v1,    // recipient side (edge type 0, BN type 1)
            Wf1, bl1, g0, b0, m0, v0);   // user side (edge type 1, BN type 0)
    }

    ep_kernel<<<(E + 63) / 64, 256, 0, stream>>>(f80_u, f80_r, eattr,
                                                 eid_r, epdst_r, eperm_r,
                                                 W1f, ep_b1,
                                                 ep_bng, ep_bnb, ep_bnm, ep_bnv,
                                                 W2f, ep_b2, ep_W3, ep_b3,
                                                 (float*)d_out, E);
}

// Round 11
// 530.954 us; speedup vs baseline: 3.0157x; 1.0366x over previous
//
#include <hip/hip_runtime.h>
#include <math.h>

#define H 128
#define BN_EPS 1e-5f

typedef __attribute__((ext_vector_type(8))) short bf16x8;
typedef __attribute__((ext_vector_type(4))) float f32x4;
typedef __attribute__((ext_vector_type(2))) float f32x2;

__device__ __forceinline__ unsigned short f2bf(float f) {
    unsigned int u = __float_as_uint(f);
    u += 0x7fffu + ((u >> 16) & 1u);
    return (unsigned short)(u >> 16);
}
__device__ __forceinline__ float bf2f(unsigned short s) {
    return __uint_as_float(((unsigned int)s) << 16);
}
__device__ __forceinline__ f32x4 mfma16(bf16x8 a, bf16x8 b, f32x4 c) {
    return __builtin_amdgcn_mfma_f32_16x16x32_bf16(a, b, c, 0, 0, 0);
}
// fp8 e4m3 (OCP on gfx950) encode/decode via HW cvt
__device__ __forceinline__ unsigned char f2fp8(float f) {
    int p = __builtin_amdgcn_cvt_pk_fp8_f32(f, f, 0, false);
    return (unsigned char)(p & 0xff);
}
// async global->LDS, 16B per lane; LDS dest = wave-uniform base + lane*16
__device__ __forceinline__ void gl_lds16(const void* g, void* l) {
    __builtin_amdgcn_global_load_lds(
        (const __attribute__((address_space(1))) unsigned int*)g,
        (__attribute__((address_space(3))) unsigned int*)l, 16, 0, 0);
}

// ---------------------------------------------------------------------------
// Weight fragment pre-transpose into MFMA B-operand layout (bf16)
// ---------------------------------------------------------------------------
__device__ __forceinline__ void wfrag_one(const float* __restrict__ src,
                                          unsigned short* __restrict__ dst,
                                          int K, int N, int idx) {
    int l = idx & 63;
    int rest = idx >> 6;
    int ntn = N >> 4;
    int nt = rest % ntn;
    int kc = rest / ntn;
    int n = nt * 16 + (l & 15);
    int k0 = kc * 32 + (l >> 4) * 8;
    bf16x8 v;
    #pragma unroll
    for (int j = 0; j < 8; ++j) {
        int k = k0 + j;
        v[j] = (short)((k < K) ? f2bf(src[(size_t)k * N + n]) : 0);
    }
    *(bf16x8*)(dst + (size_t)idx * 8) = v;
}

__global__ __launch_bounds__(256)
void wfrag_all(const float* __restrict__ W1, const float* __restrict__ W2,
               const float* __restrict__ pu, const float* __restrict__ pr,
               const float* __restrict__ Wl, const float* __restrict__ Wr,
               unsigned short* __restrict__ W1f, unsigned short* __restrict__ W2f,
               unsigned short* __restrict__ puf, unsigned short* __restrict__ prf,
               unsigned short* __restrict__ sageWf) {
    int bx = blockIdx.x;
    if (bx < 26) {
        int idx = bx * 256 + threadIdx.x;
        if (idx < 4608)      wfrag_one(W1, W1f, 272, 128, idx);          // K=272 pad 288
        else if (idx < 5632) wfrag_one(W2, W2f, 128, 64, idx - 4608);
        else if (idx < 6144) wfrag_one(pu, puf, 32, 128, idx - 5632);
        else if (idx < 6656) wfrag_one(pr, prf, 32, 128, idx - 6144);
    } else {
        int idx = (bx - 26) * 256 + threadIdx.x;   // < 16384
        int seg = idx >> 11;
        int sub = idx & 2047;
        int lt = seg >> 1;                          // layer*2+type
        int half = seg & 1;                         // 0=Wl, 1=Wr
        const float* src = (half ? Wr : Wl) + (size_t)lt * H * H;
        unsigned short* dst = sageWf + (size_t)lt * 32768 + half * 16384;
        wfrag_one(src, dst, 128, 128, sub);
    }
}

// swizzled fp8 shadow byte index for logical column col:
//   col = kc*32 + q*8 + j  ->  swz = q*32 + kc*8 + j
__device__ __forceinline__ int swz_of(int col) {
    int kc = col >> 5;
    int q = (col >> 3) & 3;
    int j = col & 7;
    return q * 32 + kc * 8 + j;
}

// ---------------------------------------------------------------------------
// Input projection via MFMA: h = x @ W + b -> bf16 h + fp8 swizzled shadow
// ---------------------------------------------------------------------------
__global__ __launch_bounds__(256)
void proj_kernel(const float* __restrict__ xu, const float* __restrict__ xr,
                 const unsigned short* __restrict__ puf, const float* __restrict__ bu,
                 const unsigned short* __restrict__ prf, const float* __restrict__ br,
                 unsigned short* __restrict__ hub, unsigned short* __restrict__ hrb,
                 unsigned char* __restrict__ h8u, unsigned char* __restrict__ h8r,
                 int Nu, int Nr, int nbu) {
    int bx = blockIdx.x;
    const float* x; const unsigned short* Wf; const float* bias;
    unsigned short* hb; unsigned char* h8; int N; int row0;
    if (bx < nbu) { x = xu; Wf = puf; bias = bu; hb = hub; h8 = h8u; N = Nu; row0 = bx * 64; }
    else          { x = xr; Wf = prf; bias = br; hb = hrb; h8 = h8r; N = Nr; row0 = (bx - nbu) * 64; }

    int tid = threadIdx.x, l = tid & 63, w = tid >> 6, l15 = l & 15, quad = l >> 4;
    int arow = row0 + w * 16 + l15;

    bf16x8 a = {0, 0, 0, 0, 0, 0, 0, 0};
    if (arow < N) {
        const float* xp = x + (size_t)arow * 32 + quad * 8;
        float4 v0 = *(const float4*)xp;
        float4 v1 = *(const float4*)(xp + 4);
        a[0] = (short)f2bf(v0.x); a[1] = (short)f2bf(v0.y);
        a[2] = (short)f2bf(v0.z); a[3] = (short)f2bf(v0.w);
        a[4] = (short)f2bf(v1.x); a[5] = (short)f2bf(v1.y);
        a[6] = (short)f2bf(v1.z); a[7] = (short)f2bf(v1.w);
    }
    f32x4 acc[8];
    #pragma unroll
    for (int nt = 0; nt < 8; ++nt) {
        bf16x8 b = *(const bf16x8*)(Wf + (size_t)(nt * 64 + l) * 8);
        acc[nt] = mfma16(a, b, (f32x4){0.f, 0.f, 0.f, 0.f});
    }
    #pragma unroll
    for (int reg = 0; reg < 4; ++reg) {
        int row = row0 + w * 16 + quad * 4 + reg;
        if (row < N) {
            #pragma unroll
            for (int nt = 0; nt < 8; ++nt) {
                int col = nt * 16 + l15;
                float v = acc[nt][reg] + bias[col];
                hb[(size_t)row * H + col] = f2bf(v);
                h8[(size_t)row * H + swz_of(col)] = f2fp8(v);
            }
        }
    }
}

// ---------------------------------------------------------------------------
// CSR build (both edge types per dispatch)
// ---------------------------------------------------------------------------
__global__ __launch_bounds__(256)
void hist_kernel(const int* __restrict__ dstR, const int* __restrict__ dstU,
                 int* __restrict__ degR, int* __restrict__ degU, int E, int EB) {
    int bx = blockIdx.x;
    const int* dst = (bx < EB) ? dstR : dstU;
    int* deg = (bx < EB) ? degR : degU;
    int e = ((bx < EB) ? bx : bx - EB) * 256 + threadIdx.x;
    if (e < E) atomicAdd(&deg[dst[e]], 1);
}

__global__ __launch_bounds__(256)
void scan1_kernel(const int* __restrict__ degR, const int* __restrict__ degU,
                  int* __restrict__ partR, int* __restrict__ partU, int Nr, int Nu, int NBr) {
    int bx = blockIdx.x;
    const int* deg = (bx < NBr) ? degR : degU;
    int* part = (bx < NBr) ? partR : partU;
    int lb = (bx < NBr) ? bx : bx - NBr;
    int N = (bx < NBr) ? Nr : Nu;
    __shared__ int s[256];
    int t = threadIdx.x;
    int i = lb * 256 + t;
    s[t] = (i < N) ? deg[i] : 0;
    __syncthreads();
    for (int o = 128; o > 0; o >>= 1) {
        if (t < o) s[t] += s[t + o];
        __syncthreads();
    }
    if (t == 0) part[lb] = s[0];
}

// scan3 computes the global prefix of raw block sums itself (no scan2)
__global__ __launch_bounds__(256)
void scan3_kernel(const int* __restrict__ degR, const int* __restrict__ degU,
                  const int* __restrict__ partR, const int* __restrict__ partU,
                  int* __restrict__ offR, int* __restrict__ offU, int Nr, int Nu, int NBr) {
    int bx = blockIdx.x;
    const int* deg = (bx < NBr) ? degR : degU;
    const int* part = (bx < NBr) ? partR : partU;
    int* off = (bx < NBr) ? offR : offU;
    int lb = (bx < NBr) ? bx : bx - NBr;
    int N = (bx < NBr) ? Nr : Nu;
    __shared__ int s[256];
    __shared__ int ps[256];
    int t = threadIdx.x;

    int pv = 0;
    if (t < lb) pv += part[t];
    if (t + 256 < lb) pv += part[t + 256];
    ps[t] = pv;
    __syncthreads();
    for (int o = 128; o > 0; o >>= 1) {
        if (t < o) ps[t] += ps[t + o];
        __syncthreads();
    }
    int pref = ps[0];

    int i = lb * 256 + t;
    int v = (i < N) ? deg[i] : 0;
    s[t] = v;
    __syncthreads();
    for (int o = 1; o < 256; o <<= 1) {
        int x = (t >= o) ? s[t - o] : 0;
        __syncthreads();
        s[t] += x;
        __syncthreads();
    }
    if (i < N) off[i] = pref + s[t] - v;
    if (i == N - 1) off[N] = pref + s[t];
}

__global__ __launch_bounds__(256)
void fill_kernel(const int* __restrict__ srcR, const int* __restrict__ dstR,
                 const int* __restrict__ srcU, const int* __restrict__ dstU,
                 const int* __restrict__ offR, const int* __restrict__ offU,
                 int* __restrict__ degR, int* __restrict__ degU,
                 int* __restrict__ eidR, int* __restrict__ eidU,
                 int* __restrict__ epermR, int* __restrict__ epdstR,
                 int E, int EB) {
    int bx = blockIdx.x;
    bool isR = bx < EB;
    const int* src = isR ? srcR : srcU;
    const int* dst = isR ? dstR : dstU;
    const int* off = isR ? offR : offU;
    int* deg = isR ? degR : degU;
    int* eid = isR ? eidR : eidU;
    int e = (isR ? bx : bx - EB) * 256 + threadIdx.x;
    if (e < E) {
        int d = dst[e];
        int p = off[d] + atomicSub(&deg[d], 1) - 1;
        eid[p] = src[e];
        if (isR) {
            epermR[p] = e;
            epdstR[p] = d;
        }
    }
}

// ---------------------------------------------------------------------------
// Fused layer: gather-mean (fp8 swizzled rows) + SAGE + BN + ReLU + residual.
// In-block degree sort (wave-0 bitonic) for uniform CSR walks.
// ---------------------------------------------------------------------------
__global__ __launch_bounds__(256)
void layer_kernel(const unsigned short* __restrict__ hu_o, const unsigned short* __restrict__ hr_o,
                  const unsigned char* __restrict__ h8u_o, const unsigned char* __restrict__ h8r_o,
                  unsigned short* __restrict__ hu_n, unsigned short* __restrict__ hr_n,
                  unsigned char* __restrict__ h8u_n, unsigned char* __restrict__ h8r_n,
                  const int* __restrict__ off_r, const int* __restrict__ eid_r,
                  const int* __restrict__ off_u, const int* __restrict__ eid_u,
                  int Nu, int Nr, int nbr,
                  const unsigned short* __restrict__ WfR, const float* __restrict__ blR,
                  const float* __restrict__ gR, const float* __restrict__ bR,
                  const float* __restrict__ mR, const float* __restrict__ vR,
                  const unsigned short* __restrict__ WfU, const float* __restrict__ blU,
                  const float* __restrict__ gU, const float* __restrict__ bU,
                  const float* __restrict__ mU, const float* __restrict__ vU) {
    int bx = blockIdx.x;
    const unsigned short* own; const unsigned char* g8; unsigned short* outp; unsigned char* out8;
    const int* off; const int* eid; const unsigned short* Wf;
    const float *bl, *bg, *bb, *bm, *bv;
    int N, row0;
    if (bx < nbr) {
        g8 = h8u_o; own = hr_o; outp = hr_n; out8 = h8r_n; off = off_r; eid = eid_r;
        Wf = WfR; bl = blR; bg = gR; bb = bR; bm = mR; bv = vR;
        N = Nr; row0 = bx * 64;
    } else {
        g8 = h8r_o; own = hu_o; outp = hu_n; out8 = h8u_n; off = off_u; eid = eid_u;
        Wf = WfU; bl = blU; bg = gU; bb = bU; bm = mU; bv = vU;
        N = Nu; row0 = (bx - nbr) * 64;
    }

    __shared__ float sc[128], sh[128], bias[128];
    __shared__ int perm[64];
    int tid = threadIdx.x;
    if (tid < 128) {
        float s = bg[tid] * rsqrtf(bv[tid] + BN_EPS);
        sc[tid] = s;
        sh[tid] = bb[tid] - bm[tid] * s;
        bias[tid] = bl[tid];
    }
    if (tid < 64) {
        int rr = row0 + tid;
        int dg = (rr < N) ? (off[rr + 1] - off[rr]) : 0;
        int key = (min(dg, 255) << 8) | tid;
        for (int k = 2; k <= 64; k <<= 1) {
            for (int j = k >> 1; j > 0; j >>= 1) {
                int p = __shfl_xor(key, j);
                bool keepmin = (((tid & j) == 0) == ((tid & k) == 0));
                key = keepmin ? (key < p ? key : p) : (key > p ? key : p);
            }
        }
        perm[tid] = key & 255;
    }
    __syncthreads();

    int l = tid & 63, w = tid >> 6, l15 = l & 15, quad = l >> 4;
    int rloc = perm[w * 16 + l15];
    int arow = row0 + rloc;
    bool rok = (arow < N);
    size_t rbase = (size_t)(rok ? arow : 0) * H;
    int s0 = rok ? off[arow] : 0;
    int s1 = rok ? off[arow + 1] : 0;

    // preload own-row bf16 fragments (in flight across the gather loop)
    bf16x8 ownfr[4];
    #pragma unroll
    for (int kc = 0; kc < 4; ++kc)
        ownfr[kc] = *(const bf16x8*)(own + rbase + kc * 32 + quad * 8);

    // gather-mean from fp8 swizzled rows: 2x16B loads per edge per lane
    float ag[4][8];
    #pragma unroll
    for (int kc = 0; kc < 4; ++kc)
        #pragma unroll
        for (int j = 0; j < 8; ++j) ag[kc][j] = 0.0f;

    for (int i = s0; i < s1; ++i) {
        int s = eid[i];
        const uint4* rp = (const uint4*)(g8 + (size_t)s * H + quad * 32);
        uint4 w0 = rp[0];   // kc0 (x,y), kc1 (z,w)
        uint4 w1 = rp[1];   // kc2 (x,y), kc3 (z,w)
        #define ACC4(word, kc, jb) { \
            f32x2 lo_ = __builtin_amdgcn_cvt_pk_f32_fp8((int)(word), false); \
            f32x2 hi_ = __builtin_amdgcn_cvt_pk_f32_fp8((int)(word), true);  \
            ag[kc][jb + 0] += lo_[0]; ag[kc][jb + 1] += lo_[1]; \
            ag[kc][jb + 2] += hi_[0]; ag[kc][jb + 3] += hi_[1]; }
        ACC4(w0.x, 0, 0) ACC4(w0.y, 0, 4) ACC4(w0.z, 1, 0) ACC4(w0.w, 1, 4)
        ACC4(w1.x, 2, 0) ACC4(w1.y, 2, 4) ACC4(w1.z, 3, 0) ACC4(w1.w, 3, 4)
        #undef ACC4
    }
    float inv = (s1 > s0) ? 1.0f / (float)(s1 - s0) : 0.0f;

    f32x4 acc[8];
    #pragma unroll
    for (int nt = 0; nt < 8; ++nt) acc[nt] = (f32x4){0.f, 0.f, 0.f, 0.f};

    #pragma unroll
    for (int kc = 0; kc < 4; ++kc) {
        bf16x8 a;
        #pragma unroll
        for (int j = 0; j < 8; ++j) a[j] = (short)f2bf(ag[kc][j] * inv);
        #pragma unroll
        for (int nt = 0; nt < 8; ++nt) {
            bf16x8 b = *(const bf16x8*)(Wf + (size_t)((kc * 8 + nt) * 64 + l) * 8);
            acc[nt] = mfma16(a, b, acc[nt]);
        }
    }
    #pragma unroll
    for (int kc = 4; kc < 8; ++kc) {
        #pragma unroll
        for (int nt = 0; nt < 8; ++nt) {
            bf16x8 b = *(const bf16x8*)(Wf + (size_t)((kc * 8 + nt) * 64 + l) * 8);
            acc[nt] = mfma16(ownfr[kc - 4], b, acc[nt]);
        }
    }

    // epilogue: bias -> BN -> ReLU -> + residual; bf16 + fp8 shadow stores
    #pragma unroll
    for (int reg = 0; reg < 4; ++reg) {
        int crow = row0 + perm[w * 16 + quad * 4 + reg];
        if (crow < N) {
            #pragma unroll
            for (int nt = 0; nt < 8; ++nt) {
                int col = nt * 16 + l15;
                float g = acc[nt][reg] + bias[col];
                g = g * sc[col] + sh[col];
                float hv = bf2f(own[(size_t)crow * H + col]);
                float o = fmaxf(g, 0.0f) + hv;
                outp[(size_t)crow * H + col] = f2bf(o);
                out8[(size_t)crow * H + swz_of(col)] = f2fp8(o);
            }
        }
    }
}

// ---------------------------------------------------------------------------
// Edge predictor via MFMA, CSR slot order; fp8 gathered A rows (registers),
// B-fragments staged through LDS once per BLOCK (double-buffered per kc):
// cuts W1f/W2f L2 traffic 4x (2.75 GB -> 0.7 GB).
// ---------------------------------------------------------------------------
__device__ __forceinline__ bf16x8 frag_fp8pair(unsigned int wa, unsigned int wb) {
    f32x2 a0 = __builtin_amdgcn_cvt_pk_f32_fp8((int)wa, false);
    f32x2 a1 = __builtin_amdgcn_cvt_pk_f32_fp8((int)wa, true);
    f32x2 b0 = __builtin_amdgcn_cvt_pk_f32_fp8((int)wb, false);
    f32x2 b1 = __builtin_amdgcn_cvt_pk_f32_fp8((int)wb, true);
    bf16x8 r;
    r[0] = (short)f2bf(a0[0]); r[1] = (short)f2bf(a0[1]);
    r[2] = (short)f2bf(a1[0]); r[3] = (short)f2bf(a1[1]);
    r[4] = (short)f2bf(b0[0]); r[5] = (short)f2bf(b0[1]);
    r[6] = (short)f2bf(b1[0]); r[7] = (short)f2bf(b1[1]);
    return r;
}

__global__ __launch_bounds__(256)
void ep_kernel(const unsigned char* __restrict__ h8u, const unsigned char* __restrict__ h8r,
               const float* __restrict__ ea,
               const int* __restrict__ slot_src, const int* __restrict__ slot_dst,
               const int* __restrict__ slot_eid,
               const unsigned short* __restrict__ W1f, const float* __restrict__ b1,
               const float* __restrict__ bng, const float* __restrict__ bnb,
               const float* __restrict__ bnm, const float* __restrict__ bnv,
               const unsigned short* __restrict__ W2f, const float* __restrict__ b2,
               const float* __restrict__ W3, const float* __restrict__ b3,
               float* __restrict__ out, int E) {
    __shared__ unsigned short h1s[64][136];                 // 19456 B
    __shared__ __align__(16) unsigned short Bst[2][4096];   // 2 x 8192 B (B-frag staging)
    __shared__ int se[64], de[64], pe[64];
    __shared__ float sc1[128], sh1[128], bi1[128];

    int tid = threadIdx.x;
    int p0 = blockIdx.x * 64;
    if (tid < 64) {
        int p = p0 + tid;
        bool v = (p < E);
        se[tid] = v ? slot_src[p] : 0;
        de[tid] = v ? slot_dst[p] : 0;
        pe[tid] = v ? slot_eid[p] : 0;
    }
    if (tid < 128) {
        float s = bng[tid] * rsqrtf(bnv[tid] + BN_EPS);
        sc1[tid] = s;
        sh1[tid] = bnb[tid] - bnm[tid] * s;
        bi1[tid] = b1[tid];
    }
    __syncthreads();

    int l = tid & 63, w = tid >> 6, l15 = l & 15, quad = l >> 4;
    int arow = w * 16 + l15;
    int eorig = pe[arow];
    bool ev = (p0 + arow < E);

    // stage chunk kc's 8 KB of W1f into Bst[buf]: each wave issues 2 x 1 KB
    #define STAGE_W1(kc, buf) { \
        int nt0 = w * 2; \
        gl_lds16(W1f + (((size_t)(kc) * 8 + nt0) * 64 + l) * 8, &Bst[buf][nt0 * 512]); \
        gl_lds16(W1f + (((size_t)(kc) * 8 + nt0 + 1) * 64 + l) * 8, &Bst[buf][(nt0 + 1) * 512]); }

    STAGE_W1(0, 0);   // kc=0 in flight

    // ---- preload all phase-1 A-fragments (fp8, 4+1 loads in flight) ----
    const uint4* sp = (const uint4*)(h8u + (size_t)se[arow] * H + quad * 32);
    const uint4* dp = (const uint4*)(h8r + (size_t)de[arow] * H + quad * 32);
    uint4 sw0 = sp[0], sw1 = sp[1];
    uint4 dw0 = dp[0], dw1 = dp[1];
    bf16x8 aea = {0, 0, 0, 0, 0, 0, 0, 0};
    if (quad < 2 && ev) {
        const float* p = ea + (size_t)eorig * 16 + quad * 8;
        float4 v0 = *(const float4*)p;
        float4 v1 = *(const float4*)(p + 4);
        aea[0] = (short)f2bf(v0.x); aea[1] = (short)f2bf(v0.y);
        aea[2] = (short)f2bf(v0.z); aea[3] = (short)f2bf(v0.w);
        aea[4] = (short)f2bf(v1.x); aea[5] = (short)f2bf(v1.y);
        aea[6] = (short)f2bf(v1.z); aea[7] = (short)f2bf(v1.w);
    }
    bf16x8 afr[9];
    afr[0] = frag_fp8pair(sw0.x, sw0.y);
    afr[1] = frag_fp8pair(sw0.z, sw0.w);
    afr[2] = frag_fp8pair(sw1.x, sw1.y);
    afr[3] = frag_fp8pair(sw1.z, sw1.w);
    afr[4] = frag_fp8pair(dw0.x, dw0.y);
    afr[5] = frag_fp8pair(dw0.z, dw0.w);
    afr[6] = frag_fp8pair(dw1.x, dw1.y);
    afr[7] = frag_fp8pair(dw1.z, dw1.w);
    afr[8] = aea;

    f32x4 acc[8];
    #pragma unroll
    for (int nt = 0; nt < 8; ++nt) acc[nt] = (f32x4){0.f, 0.f, 0.f, 0.f};

    __syncthreads();   // stage(kc=0) + A preloads complete (vmcnt drained)

    // ---- phase 1: double-buffered B staging, MFMA from LDS ----
    int buf = 0;
    #pragma unroll
    for (int kc = 0; kc < 9; ++kc) {
        if (kc < 8) STAGE_W1(kc + 1, buf ^ 1);
        #pragma unroll
        for (int nt = 0; nt < 8; ++nt) {
            bf16x8 b = *(const bf16x8*)&Bst[buf][nt * 512 + l * 8];
            acc[nt] = mfma16(afr[kc], b, acc[nt]);
        }
        __syncthreads();   // all reads of buf done; next buf's stage drained
        buf ^= 1;
    }
    #undef STAGE_W1

    // stage ALL of W2f (16 KB) into Bst while writing h1s
    {
        unsigned short* BstF = &Bst[0][0];
        #pragma unroll
        for (int j = 0; j < 4; ++j) {
            int f = w * 4 + j;
            gl_lds16(W2f + ((size_t)f * 64 + l) * 8, BstF + f * 512);
        }
    }

    // phase-1 epilogue: bias -> relu -> bn -> bf16 h1s
    #pragma unroll
    for (int nt = 0; nt < 8; ++nt) {
        #pragma unroll
        for (int reg = 0; reg < 4; ++reg) {
            int row = w * 16 + quad * 4 + reg;
            int col = nt * 16 + l15;
            float z = acc[nt][reg] + bi1[col];
            z = fmaxf(z, 0.0f);
            z = z * sc1[col] + sh1[col];
            h1s[row][col] = f2bf(z);
        }
    }
    __syncthreads();   // h1s ready + W2f staged

    // phase 2: h2 = relu(h1 @ W2 + b2), K=128, N=64 (B from LDS)
    const unsigned short* BstF = &Bst[0][0];
    f32x4 acc2[4];
    #pragma unroll
    for (int nt = 0; nt < 4; ++nt) acc2[nt] = (f32x4){0.f, 0.f, 0.f, 0.f};
    #pragma unroll
    for (int kc = 0; kc < 4; ++kc) {
        bf16x8 a2 = *(const bf16x8*)&h1s[w * 16 + l15][kc * 32 + quad * 8];
        #pragma unroll
        for (int nt = 0; nt < 4; ++nt) {
            bf16x8 b = *(const bf16x8*)(BstF + (size_t)((kc * 4 + nt) * 512) + l * 8);
            acc2[nt] = mfma16(a2, b, acc2[nt]);
        }
    }

    // phase 3: per-row dot with W3 via quad shuffle reduction
    float part[4] = {0.f, 0.f, 0.f, 0.f};
    #pragma unroll
    for (int nt = 0; nt < 4; ++nt) {
        int col = nt * 16 + l15;
        float w3v = W3[col];
        float b2v = b2[col];
        #pragma unroll
        for (int reg = 0; reg < 4; ++reg)
            part[reg] += fmaxf(acc2[nt][reg] + b2v, 0.0f) * w3v;
    }
    #pragma unroll
    for (int m = 1; m < 16; m <<= 1) {
        #pragma unroll
        for (int reg = 0; reg < 4; ++reg)
            part[reg] += __shfl_xor(part[reg], m);
    }
    if (l15 < 4) {
        int row = w * 16 + quad * 4 + l15;
        if (p0 + row < E) {
            int eo = pe[row];
            out[eo] = 1.0f / (1.0f + expf(-(part[l15] + b3[0])));
        }
    }
}

// ---------------------------------------------------------------------------
extern "C" void kernel_launch(void* const* d_in, const int* in_sizes, int n_in,
                              void* d_out, int out_size, void* d_ws, size_t ws_size,
                              hipStream_t stream) {
    const float* x_u     = (const float*)d_in[0];
    const float* x_r     = (const float*)d_in[1];
    const float* eattr   = (const float*)d_in[2];
    const int*   ei_ut   = (const int*)d_in[3];
    const int*   ei_ru   = (const int*)d_in[4];
    const float* proj_uW = (const float*)d_in[5];
    const float* proj_ub = (const float*)d_in[6];
    const float* proj_rW = (const float*)d_in[7];
    const float* proj_rb = (const float*)d_in[8];
    const float* sage_Wl = (const float*)d_in[9];
    const float* sage_bl = (const float*)d_in[10];
    const float* sage_Wr = (const float*)d_in[11];
    const float* bn_g    = (const float*)d_in[12];
    const float* bn_b    = (const float*)d_in[13];
    const float* bn_m    = (const float*)d_in[14];
    const float* bn_v    = (const float*)d_in[15];
    const float* ep_W1   = (const float*)d_in[16];
    const float* ep_b1   = (const float*)d_in[17];
    const float* ep_bng  = (const float*)d_in[18];
    const float* ep_bnb  = (const float*)d_in[19];
    const float* ep_bnm  = (const float*)d_in[20];
    const float* ep_bnv  = (const float*)d_in[21];
    const float* ep_W2   = (const float*)d_in[22];
    const float* ep_b2   = (const float*)d_in[23];
    const float* ep_W3   = (const float*)d_in[24];
    const float* ep_b3   = (const float*)d_in[25];

    int Nu = in_sizes[0] / 32;
    int Nr = in_sizes[1] / 32;
    int E  = in_sizes[3] / 2;

    // ---- workspace ----
    unsigned short* us = (unsigned short*)d_ws;
    unsigned short* h0_u = us;   us += (size_t)Nu * H;
    unsigned short* h0_r = us;   us += (size_t)Nr * H;
    unsigned short* h1_u = us;   us += (size_t)Nu * H;
    unsigned short* h1_r = us;   us += (size_t)Nr * H;
    unsigned short* W1f  = us;   us += 36864;
    unsigned short* W2f  = us;   us += 8192;
    unsigned short* puf  = us;   us += 4096;
    unsigned short* prf  = us;   us += 4096;
    unsigned short* sageWf = us; us += 131072;
    unsigned char* f80_u = (unsigned char*)us;
    unsigned char* f80_r = f80_u + (size_t)Nu * H;
    unsigned char* f81_u = f80_r + (size_t)Nr * H;
    unsigned char* f81_r = f81_u + (size_t)Nu * H;
    int* ip     = (int*)(f81_r + (size_t)Nr * H);
    int* off_r  = ip;  ip += Nr + 1;
    int* off_u  = ip;  ip += Nu + 1;
    int* deg_r  = ip;  ip += Nr;      // deg_r/deg_u contiguous (one memset)
    int* deg_u  = ip;  ip += Nu;
    int* eid_r  = ip;  ip += E;
    int* eid_u  = ip;  ip += E;
    int* eperm_r = ip; ip += E;
    int* epdst_r = ip; ip += E;
    int* part_r = ip;  ip += 512;
    int* part_u = ip;  ip += 512;

    const int* ut_src = ei_ut;
    const int* ut_dst = ei_ut + E;
    const int* ru_src = ei_ru;
    const int* ru_dst = ei_ru + E;

    int EB  = (E + 255) / 256;
    int NBr = (Nr + 255) / 256;
    int NBu = (Nu + 255) / 256;

    // ---- weight fragments ----
    wfrag_all<<<90, 256, 0, stream>>>(ep_W1, ep_W2, proj_uW, proj_rW,
                                      sage_Wl, sage_Wr,
                                      W1f, W2f, puf, prf, sageWf);

    // ---- CSR build ----
    hipMemsetAsync(deg_r, 0, (size_t)(Nr + Nu) * sizeof(int), stream);
    hist_kernel<<<2 * EB, 256, 0, stream>>>(ut_dst, ru_dst, deg_r, deg_u, E, EB);
    scan1_kernel<<<NBr + NBu, 256, 0, stream>>>(deg_r, deg_u, part_r, part_u, Nr, Nu, NBr);
    scan3_kernel<<<NBr + NBu, 256, 0, stream>>>(deg_r, deg_u, part_r, part_u,
                                                off_r, off_u, Nr, Nu, NBr);
    fill_kernel<<<2 * EB, 256, 0, stream>>>(ut_src, ut_dst, ru_src, ru_dst,
                                            off_r, off_u, deg_r, deg_u,
                                            eid_r, eid_u, eperm_r, epdst_r, E, EB);

    // ---- input projections ----
    int nbu = (Nu + 63) / 64, nbr = (Nr + 63) / 64;
    proj_kernel<<<nbu + nbr, 256, 0, stream>>>(x_u, x_r, puf, proj_ub, prf, proj_rb,
                                               h0_u, h0_r, f80_u, f80_r, Nu, Nr, nbu);

    // ---- 2 fused layers (ping-pong h0 -> h1 -> h0, fp8 shadows alongside) ----
    for (int layer = 0; layer < 2; ++layer) {
        const unsigned short* iu = (layer == 0) ? h0_u : h1_u;
        const unsigned short* ir = (layer == 0) ? h0_r : h1_r;
        const unsigned char* i8u = (layer == 0) ? f80_u : f81_u;
        const unsigned char* i8r = (layer == 0) ? f80_r : f81_r;
        unsigned short* ou = (layer == 0) ? h1_u : h0_u;
        unsigned short* orr = (layer == 0) ? h1_r : h0_r;
        unsigned char* o8u = (layer == 0) ? f81_u : f80_u;
        unsigned char* o8r = (layer == 0) ? f81_r : f80_r;

        const unsigned short* Wf0 = sageWf + ((size_t)layer * 2 + 0) * 32768;
        const unsigned short* Wf1 = sageWf + ((size_t)layer * 2 + 1) * 32768;
        const float* bl0 = sage_bl + ((size_t)layer * 2 + 0) * H;
        const float* bl1 = sage_bl + ((size_t)layer * 2 + 1) * H;
        const float* g0 = bn_g + ((size_t)layer * 2 + 0) * H;   // user BN
        const float* b0 = bn_b + ((size_t)layer * 2 + 0) * H;
        const float* m0 = bn_m + ((size_t)layer * 2 + 0) * H;
        const float* v0 = bn_v + ((size_t)layer * 2 + 0) * H;
        const float* g1 = bn_g + ((size_t)layer * 2 + 1) * H;   // recipient BN
        const float* b1 = bn_b + ((size_t)layer * 2 + 1) * H;
        const float* m1 = bn_m + ((size_t)layer * 2 + 1) * H;
        const float* v1 = bn_v + ((size_t)layer * 2 + 1) * H;

        layer_kernel<<<nbr + nbu, 256, 0, stream>>>(
            iu, ir, i8u, i8r, ou, orr, o8u, o8r,
            off_r, eid_r, off_u, eid_u,
            Nu, Nr, nbr,
            Wf0, bl0, g1, b1, m1, v1,    // recipient side (edge type 0, BN type 1)
            Wf1, bl1, g0, b0, m0, v0);   // user side (edge type 1, BN type 0)
    }

    ep_kernel<<<(E + 63) / 64, 256, 0, stream>>>(f80_u, f80_r, eattr,
                                                 eid_r, epdst_r, eperm_r,
                                                 W1f, ep_b1,
                                                 ep_bng, ep_bnb, ep_bnm, ep_bnv,
                                                 W2f, ep_b2, ep_W3, ep_b3,
                                                 (float*)d_out, E);
}